// Round 5
// baseline (690.105 us; speedup 1.0000x reference)
//
#include <hip/hip_runtime.h>
#include <hip/hip_bf16.h>

typedef __hip_bfloat16 bf16;
typedef __attribute__((ext_vector_type(4))) float f32x4;
typedef __attribute__((ext_vector_type(8))) __bf16 bf16x8;

constexpr int kE   = 1152;
constexpr int kH   = 16;
constexpr int kHD2 = 36;
constexpr int kFF  = 4304;
constexpr int kFFP = 4352;   // padded to 34*128
constexpr int kB   = 32;
constexpr int kS   = 256;
constexpr int kT   = kB * kS;      // 8192 tokens
constexpr int kQKVP = 3584;        // 3*E padded (28*128)
constexpr int kWoP  = 1280;        // E padded (10*128)
constexpr float kLambdaInit = 0.7778701f;   // 0.8 - 0.6*exp(-0.3*11)
constexpr float kRmsEps = 1e-6f;
constexpr float kSublnEps = 1e-5f;

__device__ inline void async_copy16(const void* gsrc, void* ldst) {
    __builtin_amdgcn_global_load_lds(
        (__attribute__((address_space(1))) void*)gsrc,
        (__attribute__((address_space(3))) void*)ldst, 16, 0, 0);
}

// ---------------- fused weight convert / pad, 4 elems/thread ----------------
constexpr int  kNEE  = kE * kE;                        // 1327104
constexpr long kSeg0 = (long)kQKVP * kE;               // 4128768
constexpr long kSeg1 = kSeg0 + (long)kWoP * kE;        // 5603328
constexpr long kSeg2 = kSeg1 + (long)kFFP * kE;        // 10616832
constexpr long kCvtTotal = kSeg2 + (long)kWoP * kFFP;  // 16187392  (all bounds %4==0)

__global__ __launch_bounds__(256) void convert_all(
    const float* __restrict__ Wq, const float* __restrict__ Wk,
    const float* __restrict__ Wv, const float* __restrict__ Wo,
    const float* __restrict__ f1, const float* __restrict__ f2,
    bf16* __restrict__ wqkv, bf16* __restrict__ wo,
    bf16* __restrict__ w1, bf16* __restrict__ w2)
{
    long i = ((long)blockIdx.x * 256 + threadIdx.x) * 4;
    if (i >= kCvtTotal) return;
    float4 v = make_float4(0.f, 0.f, 0.f, 0.f);
    bf16* dst;
    if (i < kSeg0) {                       // wqkv [3584][1152], rows>=3456 zero
        long j = i;
        if (j < 3L * kNEE) {
            const float* src = (j < kNEE) ? Wq : (j < 2L * kNEE) ? Wk : Wv;
            v = *(const float4*)(src + (j % kNEE));
        }
        dst = wqkv + j;
    } else if (i < kSeg1) {                // wo [1280][1152], rows>=1152 zero
        long j = i - kSeg0;
        if (j < kNEE) v = *(const float4*)(Wo + j);
        dst = wo + j;
    } else if (i < kSeg2) {                // w1 [4352][1152], rows>=4304 zero
        long j = i - kSeg1;
        if (j < (long)kFF * kE) v = *(const float4*)(f1 + j);
        dst = w1 + j;
    } else {                               // w2 [1280][4352], pad rows/cols zero
        long j = i - kSeg2;
        int n = (int)(j / kFFP), k = (int)(j - (long)n * kFFP);
        if (n < kE && k < kFF) v = *(const float4*)(f2 + (long)n * kFF + k);
        dst = w2 + j;
    }
    union { uint2 u; bf16 e[4]; } o;
    o.e[0] = __float2bfloat16(v.x); o.e[1] = __float2bfloat16(v.y);
    o.e[2] = __float2bfloat16(v.z); o.e[3] = __float2bfloat16(v.w);
    *(uint2*)dst = o.u;
}

__global__ __launch_bounds__(256) void prep_bias(
    const float* __restrict__ bq, const float* __restrict__ bk,
    const float* __restrict__ bv, const float* __restrict__ fb,
    float* __restrict__ bqkv, float* __restrict__ fbp)
{
    int i = blockIdx.x * 256 + threadIdx.x;
    if (i < kQKVP) {
        float v = (i < kE) ? bq[i] : (i < 2 * kE) ? bk[i - kE]
                : (i < 3 * kE) ? bv[i - 2 * kE] : 0.f;
        bqkv[i] = v;
    }
    if (i < kFFP) fbp[i] = (i < kFF) ? fb[i] : 0.f;
}

// ---------------- RMSNorm (fp32 in -> bf16 out) ----------------
__global__ __launch_bounds__(256) void rmsnorm_kernel(
    const float* __restrict__ x, const float* __restrict__ w,
    bf16* __restrict__ out, float eps)
{
    int row = blockIdx.x;
    const float* xr = x + (size_t)row * kE;
    float vals[5];
    float ss = 0.f;
    int n = 0;
    for (int j = threadIdx.x; j < kE; j += 256) {
        float v = xr[j];
        vals[n++] = v;
        ss += v * v;
    }
    for (int m = 32; m > 0; m >>= 1) ss += __shfl_xor(ss, m, 64);
    __shared__ float red[4];
    if ((threadIdx.x & 63) == 0) red[threadIdx.x >> 6] = ss;
    __syncthreads();
    float tot = red[0] + red[1] + red[2] + red[3];
    float scale = rsqrtf(tot / (float)kE + eps);
    n = 0;
    for (int j = threadIdx.x; j < kE; j += 256)
        out[(size_t)row * kE + j] = __float2bfloat16(vals[n++] * scale * w[j]);
}

// ---- bf16 NT GEMM, 128x128 tile, BK=32, 4 waves, dbuf, 3 blocks/CU ----
// A [M,ldk] bf16 row-major, Bw [N,ldk] bf16 row-major (N padded to 128).
// EPI: 0 bf16+bias | 1 gelu bf16+bias | 2 fp32+bias+add, stride/guard Nreal.
// 32 KiB LDS/block -> 3 blocks/CU for TLP; counted vmcnt (never 0 mid-loop).
#define GBAR() do { asm volatile("" ::: "memory"); \
                    __builtin_amdgcn_s_barrier();  \
                    asm volatile("" ::: "memory"); } while (0)

template <int EPI>
__global__ __launch_bounds__(256, 3) void gemm128(
    const bf16* __restrict__ A, const bf16* __restrict__ Bw,
    const float* __restrict__ bias, const float* add, void* out,
    int N, int Nreal, int K, int ldk)
{
    // [parity][mat A=0/B=1][128 rows x 64 B], swizzled 16B slots (4/row)
    __shared__ __align__(16) char sm[2][2][8192];

    const int tid  = threadIdx.x;
    const int lane = tid & 63;
    const int wave = tid >> 6;
    const int wm   = wave >> 1;
    const int wn   = wave & 1;
    const int q4   = lane >> 4;
    const int l16  = lane & 15;

    // bijective XCD-aware block swizzle (m204 variant)
    const int nwg  = gridDim.x * gridDim.y;
    const int orig = blockIdx.y * gridDim.x + blockIdx.x;
    const int qq = nwg >> 3, rr = nwg & 7;
    const int xcd = orig & 7, loc = orig >> 3;
    const int wg = (xcd < rr ? xcd * (qq + 1) : rr * (qq + 1) + (xcd - rr) * qq) + loc;
    const int bn = wg % gridDim.x;
    const int bm = wg / gridDim.x;

    const int NT = K >> 5;

    // staging: linear LDS dest (gload_lds constraint), pre-swizzled global col.
    // sigma(row) = (row&3) ^ ((row>>2)&3); LDS[row][s] = Glb[row][s ^ sigma(row)].
    // Invariant under row += 64, so one per-thread source offset for both rounds.
    const int trow = tid >> 2;                               // 0..63
    const int tswz = (((tid & 3) ^ (trow & 3) ^ ((trow >> 2) & 3)) << 4);
    const size_t rs = (size_t)ldk * 2;
    const char* aG = (const char*)A + (size_t)(bm * 128 + trow) * rs + tswz;
    const char* bG = (const char*)Bw + (size_t)(bn * 128 + trow) * rs + tswz;

#define STAGE(mat, G, par, tt)                                                  \
    {                                                                           \
        const size_t kb = (size_t)(tt) * 64;                                    \
        async_copy16(G + kb,           sm[par][mat] + tid * 16);                \
        async_copy16(G + 64 * rs + kb, sm[par][mat] + tid * 16 + 4096);         \
    }

    // read swizzle: sigma(row) for row = {wm|wn}*64 + mi*16 + l16 reduces to
    // (l16&3) ^ ((l16>>2)&3)  (mi*16, wm*64 vanish mod 4 at both bit fields)
    const int sw = ((q4 ^ (l16 & 3) ^ ((l16 >> 2) & 3)) << 4);
    const int aoff = (wm * 64 + l16) * 64 + sw;
    const int boff = (wn * 64 + l16) * 64 + sw;

    f32x4 acc[4][4] = {};
    bf16x8 afr[4], bfr[4];

    // prologue: tiles 0,1 staged into par 0,1; wait tile 0 (4 newest in flight)
    STAGE(0, aG, 0, 0);
    STAGE(1, bG, 0, 0);
    if (NT > 1) {
        STAGE(0, aG, 1, 1);
        STAGE(1, bG, 1, 1);
        asm volatile("s_waitcnt vmcnt(4)" ::: "memory");
    } else {
        asm volatile("s_waitcnt vmcnt(0)" ::: "memory");
    }
    GBAR();

    for (int t = 0; t < NT; ++t) {
        const int par = t & 1;
        const char* sA = sm[par][0];
        const char* sB = sm[par][1];

        // read all fragments for this K-tile (8 x ds_read_b128)
#pragma unroll
        for (int mi = 0; mi < 4; ++mi)
            afr[mi] = *(const bf16x8*)(sA + mi * 1024 + aoff);
#pragma unroll
        for (int ni = 0; ni < 4; ++ni)
            bfr[ni] = *(const bf16x8*)(sB + ni * 1024 + boff);
        // drain my reads so the barrier certifies buffer[par] fully consumed
        asm volatile("s_waitcnt lgkmcnt(0)" ::: "memory");
        GBAR();

        // stage t+2 into this (now consumed) buffer; runs under the MFMAs
        if (t + 2 < NT) {
            STAGE(0, aG, par, t + 2);
            STAGE(1, bG, par, t + 2);
        }
        __builtin_amdgcn_s_setprio(1);
#pragma unroll
        for (int mi = 0; mi < 4; ++mi)
#pragma unroll
            for (int ni = 0; ni < 4; ++ni)
                acc[mi][ni] = __builtin_amdgcn_mfma_f32_16x16x32_bf16(
                    afr[mi], bfr[ni], acc[mi][ni], 0, 0, 0);
        __builtin_amdgcn_s_setprio(0);
        if (t + 2 < NT) {
            // outstanding: tile t+1 (4) + tile t+2 (4); drain oldest 4
            asm volatile("s_waitcnt vmcnt(4)" ::: "memory");
        } else {
            asm volatile("s_waitcnt vmcnt(0)" ::: "memory");
        }
        GBAR();
    }
#undef STAGE

    // ---- epilogue: per-wave 64x64 at (wm,wn) ----
    const int growb = bm * 128 + wm * 64;
    const int gcolb = bn * 128 + wn * 64;
#pragma unroll
    for (int mi = 0; mi < 4; ++mi) {
#pragma unroll
        for (int ni = 0; ni < 4; ++ni) {
            const int gcol = gcolb + ni * 16 + l16;
            float bv;
            if (EPI == 2) bv = (gcol < Nreal) ? bias[gcol] : 0.f;
            else          bv = bias[gcol];
#pragma unroll
            for (int r = 0; r < 4; ++r) {
                const int grow = growb + mi * 16 + q4 * 4 + r;
                float v = acc[mi][ni][r] + bv;
                if (EPI == 0) {
                    ((bf16*)out)[(size_t)grow * N + gcol] = __float2bfloat16(v);
                } else if (EPI == 1) {
                    float u = 1.5957691216f * (v + 0.044715f * v * v * v);
                    float g = v / (1.f + __expf(-u));
                    ((bf16*)out)[(size_t)grow * N + gcol] = __float2bfloat16(g);
                } else {
                    if (gcol < Nreal) {
                        size_t idx = (size_t)grow * Nreal + gcol;
                        ((float*)out)[idx] = v + add[idx];
                    }
                }
            }
        }
    }
}

// ---------------- MFMA differential attention + subln ----------------
union U8 { bf16x8 v; uint4 u4; uint2 u2[2]; unsigned short e[8]; };

__global__ __launch_bounds__(256) void attn_mfma(
    const bf16* __restrict__ qkv,
    const float* __restrict__ lq1, const float* __restrict__ lk1,
    const float* __restrict__ lq2, const float* __restrict__ lk2,
    const float* __restrict__ subln_w, bf16* __restrict__ out)
{
    __shared__ __align__(16) bf16 Kp[256 * 136];   // 69632 B
    __shared__ __align__(16) bf16 VT[80 * 264];    // 42240 B
    __shared__ __align__(16) bf16 Pb[4 * 16 * 264];// 33792 B   (total 145664)

    const int tid = threadIdx.x;
    const int h = blockIdx.x & 15;
    const int b = blockIdx.x >> 4;
    const size_t tokbase = (size_t)b * kS;

    float s1 = 0.f, s2 = 0.f;
    for (int i = 0; i < kHD2; ++i) { s1 += lq1[i] * lk1[i]; s2 += lq2[i] * lk2[i]; }
    const float lam = __expf(s1) - __expf(s2) + kLambdaInit;

    for (int c = tid; c < 256 * 34; c += 256) {
        int row = c / 34, s4 = (c - row * 34) * 4;
        uint2 val = make_uint2(0u, 0u);
        const bf16* kg = qkv + (tokbase + row) * kQKVP + kE + h * 72;
        if (s4 < 36)                    val = *(const uint2*)(kg + s4);
        else if (s4 >= 64 && s4 < 100)  val = *(const uint2*)(kg + s4 - 28);
        *(uint2*)(Kp + row * 136 + s4) = val;
    }
    for (int c = tid; c < 256 * 18; c += 256) {
        int j = c / 18, s4 = (c - j * 18) * 4;
        union { uint2 u; unsigned short e[4]; } uu;
        uu.u = *(const uint2*)(qkv + (tokbase + j) * kQKVP + 2 * kE + h * 72 + s4);
#pragma unroll
        for (int x = 0; x < 4; ++x)
            ((unsigned short*)VT)[(s4 + x) * 264 + j] = uu.e[x];
    }
    for (int c = tid; c < 8 * 256; c += 256) {
        int d = 72 + (c >> 8), j = c & 255;
        ((unsigned short*)VT)[d * 264 + j] = 0;
    }
    __syncthreads();

    const int w = tid >> 6, lane = tid & 63, quad = lane >> 4, l16 = lane & 15;
    bf16* Pw = Pb + w * (16 * 264);
    const float sc = 0.117851130f;            // 1/sqrt(72)
    const float oscale = 1.f - kLambdaInit;

    float sw[5];
#pragma unroll
    for (int dt = 0; dt < 5; ++dt) {
        int d = dt * 16 + l16;
        sw[dt] = (d < 72) ? subln_w[d] : 0.f;
    }

    for (int s = 0; s < 4; ++s) {
        const int q0 = w * 64 + s * 16;
        const bf16* qg = qkv + (tokbase + q0 + l16) * kQKVP + h * 72;
        U8 qe0, qe1, qo0, qo1;
        qe0.u4 = *(const uint4*)(qg + quad * 8);
        qe1.u4 = *(const uint4*)(qg + 32);
        qo0.u2[0] = *(const uint2*)(qg + 36 + quad * 8);
        qo0.u2[1] = *(const uint2*)(qg + 40 + quad * 8);
        qo1.u2[0] = *(const uint2*)(qg + 68);
        qo1.u2[1] = *(const uint2*)(qg + 72);
#pragma unroll
        for (int j = 0; j < 8; ++j) {
            bool keep = (quad == 0) && (j < 4);
            if (!keep) { qe1.e[j] = 0; qo1.e[j] = 0; }
        }

        f32x4 se[16], so[16];
#pragma unroll
        for (int t = 0; t < 16; ++t) { se[t] = f32x4{0,0,0,0}; so[t] = f32x4{0,0,0,0}; }
#pragma unroll
        for (int t = 0; t < 16; ++t) {
            const bf16* kr = Kp + (t * 16 + l16) * 136;
            bf16x8 ke0 = *(const bf16x8*)(kr + quad * 8);
            bf16x8 ke1 = *(const bf16x8*)(kr + 32 + quad * 8);
            bf16x8 ko0 = *(const bf16x8*)(kr + 64 + quad * 8);
            bf16x8 ko1 = *(const bf16x8*)(kr + 96 + quad * 8);
            se[t] = __builtin_amdgcn_mfma_f32_16x16x32_bf16(qe0.v, ke0, se[t], 0, 0, 0);
            se[t] = __builtin_amdgcn_mfma_f32_16x16x32_bf16(qe1.v, ke1, se[t], 0, 0, 0);
            so[t] = __builtin_amdgcn_mfma_f32_16x16x32_bf16(qo0.v, ko0, so[t], 0, 0, 0);
            so[t] = __builtin_amdgcn_mfma_f32_16x16x32_bf16(qo1.v, ko1, so[t], 0, 0, 0);
        }

#pragma unroll
        for (int reg = 0; reg < 4; ++reg) {
            float me = -1e30f, mo = -1e30f;
#pragma unroll
            for (int t = 0; t < 16; ++t) {
                me = fmaxf(me, se[t][reg]);
                mo = fmaxf(mo, so[t][reg]);
            }
#pragma unroll
            for (int m = 1; m < 16; m <<= 1) {
                me = fmaxf(me, __shfl_xor(me, m, 64));
                mo = fmaxf(mo, __shfl_xor(mo, m, 64));
            }
            float sume = 0.f, sumo = 0.f;
#pragma unroll
            for (int t = 0; t < 16; ++t) {
                float pe = __expf((se[t][reg] - me) * sc);
                float po = __expf((so[t][reg] - mo) * sc);
                se[t][reg] = pe; sume += pe;
                so[t][reg] = po; sumo += po;
            }
#pragma unroll
            for (int m = 1; m < 16; m <<= 1) {
                sume += __shfl_xor(sume, m, 64);
                sumo += __shfl_xor(sumo, m, 64);
            }
            const float ie = 1.f / sume, io = lam / sumo;
            bf16* prow = Pw + (quad * 4 + reg) * 264;
#pragma unroll
            for (int t = 0; t < 16; ++t) {
                float p = se[t][reg] * ie - so[t][reg] * io;
                prow[t * 16 + l16] = __float2bfloat16(p);
            }
        }

        f32x4 oacc[5];
#pragma unroll
        for (int dt = 0; dt < 5; ++dt) oacc[dt] = f32x4{0,0,0,0};
#pragma unroll
        for (int k0 = 0; k0 < 256; k0 += 32) {
            bf16x8 pf = *(const bf16x8*)(Pw + l16 * 264 + k0 + quad * 8);
#pragma unroll
            for (int dt = 0; dt < 5; ++dt) {
                bf16x8 vf = *(const bf16x8*)(VT + (dt * 16 + l16) * 264 + k0 + quad * 8);
                oacc[dt] = __builtin_amdgcn_mfma_f32_16x16x32_bf16(pf, vf, oacc[dt], 0, 0, 0);
            }
        }

#pragma unroll
        for (int reg = 0; reg < 4; ++reg) {
            float ssq = 0.f;
#pragma unroll
            for (int dt = 0; dt < 5; ++dt) {
                float v = oacc[dt][reg];
                if (dt < 4 || l16 < 8) ssq += v * v;
            }
#pragma unroll
            for (int m = 1; m < 16; m <<= 1) ssq += __shfl_xor(ssq, m, 64);
            float scale = rsqrtf(ssq * (1.f / 72.f) + kSublnEps) * oscale;
            size_t orow = (tokbase + q0 + quad * 4 + reg) * (size_t)kE + h * 72;
#pragma unroll
            for (int dt = 0; dt < 5; ++dt) {
                int d = dt * 16 + l16;
                if (d < 72)
                    out[orow + d] = __float2bfloat16(oacc[dt][reg] * scale * sw[dt]);
            }
        }
    }
}

// ---------------- launch ----------------
extern "C" void kernel_launch(void* const* d_in, const int* in_sizes, int n_in,
                              void* d_out, int out_size, void* d_ws, size_t ws_size,
                              hipStream_t stream)
{
    const float* hidden = (const float*)d_in[0];
    const float* Wq = (const float*)d_in[1];
    const float* bq = (const float*)d_in[2];
    const float* Wk = (const float*)d_in[3];
    const float* bk = (const float*)d_in[4];
    const float* Wv = (const float*)d_in[5];
    const float* bv = (const float*)d_in[6];
    const float* Wo = (const float*)d_in[7];
    const float* bo = (const float*)d_in[8];
    const float* lq1 = (const float*)d_in[9];
    const float* lk1 = (const float*)d_in[10];
    const float* lq2 = (const float*)d_in[11];
    const float* lk2 = (const float*)d_in[12];
    const float* subln_w = (const float*)d_in[13];
    const float* rms1_w = (const float*)d_in[14];
    const float* rms2_w = (const float*)d_in[15];
    const float* fc1_w = (const float*)d_in[16];
    const float* fc1_b = (const float*)d_in[17];
    const float* fc2_w = (const float*)d_in[18];
    const float* fc2_b = (const float*)d_in[19];
    float* outp = (float*)d_out;

    char* wsp = (char*)d_ws;
    size_t off = 0;
    auto alloc = [&](size_t bytes) {
        char* p = wsp + off;
        off += (bytes + 255) & ~(size_t)255;
        return p;
    };
    bf16* wqkv = (bf16*)alloc((size_t)kQKVP * kE * 2);
    bf16* wo   = (bf16*)alloc((size_t)kWoP * kE * 2);
    bf16* w1   = (bf16*)alloc((size_t)kFFP * kE * 2);
    bf16* w2   = (bf16*)alloc((size_t)kWoP * kFFP * 2);
    float* bqkv = (float*)alloc((size_t)kQKVP * 4);
    float* b1   = (float*)alloc((size_t)kFFP * 4);
    bf16* xb    = (bf16*)alloc((size_t)kT * kE * 2);
    bf16* big   = (bf16*)alloc((size_t)kT * kFFP * 2);
    (void)ws_size;

    convert_all<<<(int)((kCvtTotal / 4 + 255) / 256), 256, 0, stream>>>(
        Wq, Wk, Wv, Wo, fc1_w, fc2_w, wqkv, wo, w1, w2);
    prep_bias<<<17, 256, 0, stream>>>(bq, bk, bv, fc1_b, bqkv, b1);

    rmsnorm_kernel<<<kT, 256, 0, stream>>>(hidden, rms1_w, xb, kRmsEps);
    // qkv projection: [8192,1152] x [3584,1152]^T -> big [8192,3584] bf16
    gemm128<0><<<dim3(kQKVP / 128, kT / 128), 256, 0, stream>>>(
        xb, wqkv, bqkv, nullptr, big, kQKVP, kQKVP, kE, kE);
    attn_mfma<<<kB * kH, 256, 0, stream>>>(
        big, lq1, lk1, lq2, lk2, subln_w, xb);
    // h = attn @ Wo^T + bo + hidden -> d_out (fp32), N padded 1280, real 1152
    gemm128<2><<<dim3(kWoP / 128, kT / 128), 256, 0, stream>>>(
        xb, wo, bo, hidden, d_out, kWoP, kE, kE, kE);
    rmsnorm_kernel<<<kT, 256, 0, stream>>>(outp, rms2_w, xb, kRmsEps);
    gemm128<1><<<dim3(kFFP / 128, kT / 128), 256, 0, stream>>>(
        xb, w1, b1, nullptr, big, kFFP, kFFP, kE, kE);
    // fc2: [8192,4352] x [1280,4352]^T; += h (in d_out) + bias -> d_out
    gemm128<2><<<dim3(kWoP / 128, kT / 128), 256, 0, stream>>>(
        big, w2, fc2_b, outp, d_out, kWoP, kE, kFFP, kFFP);
}

// Round 6
// 649.438 us; speedup vs baseline: 1.0626x; 1.0626x over previous
//
#include <hip/hip_runtime.h>
#include <hip/hip_bf16.h>

typedef __hip_bfloat16 bf16;
typedef __attribute__((ext_vector_type(4))) float f32x4;
typedef __attribute__((ext_vector_type(8))) __bf16 bf16x8;

constexpr int kE   = 1152;
constexpr int kH   = 16;
constexpr int kHD2 = 36;
constexpr int kFF  = 4304;
constexpr int kFFP = 4352;   // padded to 68*64
constexpr int kB   = 32;
constexpr int kS   = 256;
constexpr int kT   = kB * kS;      // 8192 tokens
constexpr int kQKV = 3456;         // 3*E (54*64, exact)
constexpr float kLambdaInit = 0.7778701f;   // 0.8 - 0.6*exp(-0.3*11)
constexpr float kRmsEps = 1e-6f;
constexpr float kSublnEps = 1e-5f;

__device__ inline void async_copy16(const void* gsrc, void* ldst) {
    __builtin_amdgcn_global_load_lds(
        (__attribute__((address_space(1))) void*)gsrc,
        (__attribute__((address_space(3))) void*)ldst, 16, 0, 0);
}

// ---------------- fused weight convert / pad, 4 elems/thread ----------------
constexpr int  kNEE  = kE * kE;                        // 1327104
constexpr long kSeg0 = 3L * kNEE;                      // wqkv [3456][1152]
constexpr long kSeg1 = kSeg0 + kNEE;                   // wo   [1152][1152]
constexpr long kSeg2 = kSeg1 + (long)kFFP * kE;        // w1   [4352][1152]
constexpr long kCvtTotal = kSeg2 + (long)kE * kFFP;    // w2   [1152][4352]

__global__ __launch_bounds__(256) void convert_all(
    const float* __restrict__ Wq, const float* __restrict__ Wk,
    const float* __restrict__ Wv, const float* __restrict__ Wo,
    const float* __restrict__ f1, const float* __restrict__ f2,
    bf16* __restrict__ wqkv, bf16* __restrict__ wo,
    bf16* __restrict__ w1, bf16* __restrict__ w2)
{
    long i = ((long)blockIdx.x * 256 + threadIdx.x) * 4;
    if (i >= kCvtTotal) return;
    float4 v = make_float4(0.f, 0.f, 0.f, 0.f);
    bf16* dst;
    if (i < kSeg0) {                       // wqkv, exact (no pad)
        long j = i;
        const float* src = (j < kNEE) ? Wq : (j < 2L * kNEE) ? Wk : Wv;
        v = *(const float4*)(src + (j % kNEE));
        dst = wqkv + j;
    } else if (i < kSeg1) {                // wo, exact
        long j = i - kSeg0;
        v = *(const float4*)(Wo + j);
        dst = wo + j;
    } else if (i < kSeg2) {                // w1 [4352][1152], rows>=4304 zero
        long j = i - kSeg1;
        if (j < (long)kFF * kE) v = *(const float4*)(f1 + j);
        dst = w1 + j;
    } else {                               // w2 [1152][4352], cols>=4304 zero
        long j = i - kSeg2;
        int n = (int)(j / kFFP), k = (int)(j - (long)n * kFFP);
        if (k < kFF) v = *(const float4*)(f2 + (long)n * kFF + k);
        dst = w2 + j;
    }
    union { uint2 u; bf16 e[4]; } o;
    o.e[0] = __float2bfloat16(v.x); o.e[1] = __float2bfloat16(v.y);
    o.e[2] = __float2bfloat16(v.z); o.e[3] = __float2bfloat16(v.w);
    *(uint2*)dst = o.u;
}

__global__ __launch_bounds__(256) void prep_bias(
    const float* __restrict__ bq, const float* __restrict__ bk,
    const float* __restrict__ bv, const float* __restrict__ fb,
    float* __restrict__ bqkv, float* __restrict__ fbp)
{
    int i = blockIdx.x * 256 + threadIdx.x;
    if (i < kQKV) {
        float v = (i < kE) ? bq[i] : (i < 2 * kE) ? bk[i - kE] : bv[i - 2 * kE];
        bqkv[i] = v;
    }
    if (i < kFFP) fbp[i] = (i < kFF) ? fb[i] : 0.f;
}

// ---------------- RMSNorm (fp32 in -> bf16 out) ----------------
__global__ __launch_bounds__(256) void rmsnorm_kernel(
    const float* __restrict__ x, const float* __restrict__ w,
    bf16* __restrict__ out, float eps)
{
    int row = blockIdx.x;
    const float* xr = x + (size_t)row * kE;
    float vals[5];
    float ss = 0.f;
    int n = 0;
    for (int j = threadIdx.x; j < kE; j += 256) {
        float v = xr[j];
        vals[n++] = v;
        ss += v * v;
    }
    for (int m = 32; m > 0; m >>= 1) ss += __shfl_xor(ss, m, 64);
    __shared__ float red[4];
    if ((threadIdx.x & 63) == 0) red[threadIdx.x >> 6] = ss;
    __syncthreads();
    float tot = red[0] + red[1] + red[2] + red[3];
    float scale = rsqrtf(tot / (float)kE + eps);
    n = 0;
    for (int j = threadIdx.x; j < kE; j += 256)
        out[(size_t)row * kE + j] = __float2bfloat16(vals[n++] * scale * w[j]);
}

// ---- bf16 NT GEMM, 128Mx64N tile, BK=64, 4 waves, dbuf, 3 blocks/CU ----
// A [M,ldk] bf16 row-major, Bw [N,ldk] bf16 row-major (N mult of 64).
// EPI: 0 bf16+bias | 1 gelu bf16+bias | 2 fp32+bias+add.
// 48 KiB LDS (128B rows: conflict-free swizzle) -> 3 blocks/CU TLP;
// counted vmcnt(6) mid-loop (6 gload_lds per tile: 4 A + 2 B).
#define GBAR() do { asm volatile("" ::: "memory"); \
                    __builtin_amdgcn_s_barrier();  \
                    asm volatile("" ::: "memory"); } while (0)

template <int EPI>
__global__ __launch_bounds__(256, 3) void gemm128(
    const bf16* __restrict__ A, const bf16* __restrict__ Bw,
    const float* __restrict__ bias, const float* add, void* out,
    int N, int K, int ldk)
{
    // [parity]: A 128 rows x 128B at 0, B 64 rows x 128B at 16384
    __shared__ __align__(16) char sm[2][24576];

    const int tid  = threadIdx.x;
    const int lane = tid & 63;
    const int wave = tid >> 6;
    const int wm   = wave >> 1;        // 0,1: M-half (64 rows)
    const int wn   = wave & 1;         // 0,1: N-half (32 cols)
    const int q4   = lane >> 4;
    const int l16  = lane & 15;

    // bijective XCD-aware block swizzle (m204 variant)
    const int nwg  = gridDim.x * gridDim.y;
    const int orig = blockIdx.y * gridDim.x + blockIdx.x;
    const int qq = nwg >> 3, rr = nwg & 7;
    const int xcd = orig & 7, loc = orig >> 3;
    const int wg = (xcd < rr ? xcd * (qq + 1) : rr * (qq + 1) + (xcd - rr) * qq) + loc;
    const int bn = wg % gridDim.x;
    const int bm = wg / gridDim.x;

    const int NT = K >> 6;

    // staging: linear LDS dest (gload_lds constraint), pre-swizzled global col.
    // LDS[row][slot] holds global (row, slot ^ (row&7)); 16B slots, 8 per row.
    const int trow = tid >> 3;                               // 0..31
    const int tswz = ((tid & 7) ^ (trow & 7)) << 4;
    const size_t rs = (size_t)ldk * 2;
    const char* aG = (const char*)A + (size_t)(bm * 128 + trow) * rs + tswz;
    const char* bG = (const char*)Bw + (size_t)(bn * 64 + trow) * rs + tswz;

#define STAGE(par, tt)                                                          \
    {                                                                           \
        const size_t kb = (size_t)(tt) * 128;                                   \
        async_copy16(aG + kb,           sm[par] + tid * 16);                    \
        async_copy16(aG + 32 * rs + kb, sm[par] + tid * 16 + 4096);             \
        async_copy16(aG + 64 * rs + kb, sm[par] + tid * 16 + 8192);             \
        async_copy16(aG + 96 * rs + kb, sm[par] + tid * 16 + 12288);            \
        async_copy16(bG + kb,           sm[par] + tid * 16 + 16384);            \
        async_copy16(bG + 32 * rs + kb, sm[par] + tid * 16 + 20480);            \
    }

    // per-lane ds_read offsets (swizzle-matched; rows == l16 mod 8)
    int aoff[2], boff[2];
#pragma unroll
    for (int kh = 0; kh < 2; ++kh) {
        const int sw = (((kh << 2) + q4) ^ (l16 & 7)) << 4;
        aoff[kh] = (wm * 64 + l16) * 128 + sw;
        boff[kh] = 16384 + (wn * 32 + l16) * 128 + sw;
    }

    f32x4 acc[4][2] = {};
    bf16x8 afr[4][2], bfr[2][2];

    // prologue: tiles 0,1 staged into par 0,1; wait tile 0 (6 newest in flight)
    STAGE(0, 0);
    if (NT > 1) {
        STAGE(1, 1);
        asm volatile("s_waitcnt vmcnt(6)" ::: "memory");
    } else {
        asm volatile("s_waitcnt vmcnt(0)" ::: "memory");
    }
    GBAR();

    for (int t = 0; t < NT; ++t) {
        const int par = t & 1;
        const char* sB0 = sm[par];

        // read all fragments for this K-tile (12 x ds_read_b128)
#pragma unroll
        for (int mi = 0; mi < 4; ++mi)
#pragma unroll
            for (int kh = 0; kh < 2; ++kh)
                afr[mi][kh] = *(const bf16x8*)(sB0 + mi * 2048 + aoff[kh]);
#pragma unroll
        for (int ni = 0; ni < 2; ++ni)
#pragma unroll
            for (int kh = 0; kh < 2; ++kh)
                bfr[ni][kh] = *(const bf16x8*)(sB0 + ni * 2048 + boff[kh]);
        // drain my reads so the barrier certifies buffer[par] fully consumed
        asm volatile("s_waitcnt lgkmcnt(0)" ::: "memory");
        GBAR();

        // stage t+2 into this (now consumed) buffer; runs under the MFMAs
        if (t + 2 < NT) STAGE(par, t + 2);
        __builtin_amdgcn_s_setprio(1);
#pragma unroll
        for (int mi = 0; mi < 4; ++mi)
#pragma unroll
            for (int ni = 0; ni < 2; ++ni)
#pragma unroll
                for (int kh = 0; kh < 2; ++kh)
                    acc[mi][ni] = __builtin_amdgcn_mfma_f32_16x16x32_bf16(
                        afr[mi][kh], bfr[ni][kh], acc[mi][ni], 0, 0, 0);
        __builtin_amdgcn_s_setprio(0);
        if (t + 2 < NT) {
            // outstanding: tile t+1 (6) + tile t+2 (6); drain oldest 6
            asm volatile("s_waitcnt vmcnt(6)" ::: "memory");
        } else {
            asm volatile("s_waitcnt vmcnt(0)" ::: "memory");
        }
        GBAR();
    }
#undef STAGE

    // ---- epilogue: per-wave 64x32 at (wm,wn) ----
    const int growb = bm * 128 + wm * 64;
    const int gcolb = bn * 64 + wn * 32;
#pragma unroll
    for (int mi = 0; mi < 4; ++mi) {
#pragma unroll
        for (int ni = 0; ni < 2; ++ni) {
            const int gcol = gcolb + ni * 16 + l16;
            const float bv = bias[gcol];
#pragma unroll
            for (int r = 0; r < 4; ++r) {
                const int grow = growb + mi * 16 + q4 * 4 + r;
                float v = acc[mi][ni][r] + bv;
                size_t idx = (size_t)grow * N + gcol;
                if (EPI == 0) {
                    ((bf16*)out)[idx] = __float2bfloat16(v);
                } else if (EPI == 1) {
                    float u = 1.5957691216f * (v + 0.044715f * v * v * v);
                    float g = v / (1.f + __expf(-u));
                    ((bf16*)out)[idx] = __float2bfloat16(g);
                } else {
                    ((float*)out)[idx] = v + add[idx];
                }
            }
        }
    }
}

// ---------------- MFMA differential attention + subln ----------------
union U8 { bf16x8 v; uint4 u4; uint2 u2[2]; unsigned short e[8]; };

__global__ __launch_bounds__(256) void attn_mfma(
    const bf16* __restrict__ qkv,
    const float* __restrict__ lq1, const float* __restrict__ lk1,
    const float* __restrict__ lq2, const float* __restrict__ lk2,
    const float* __restrict__ subln_w, bf16* __restrict__ out)
{
    __shared__ __align__(16) bf16 Kp[256 * 136];   // 69632 B
    __shared__ __align__(16) bf16 VT[80 * 264];    // 42240 B
    __shared__ __align__(16) bf16 Pb[4 * 16 * 264];// 33792 B   (total 145664)

    const int tid = threadIdx.x;
    const int h = blockIdx.x & 15;
    const int b = blockIdx.x >> 4;
    const size_t tokbase = (size_t)b * kS;

    float s1 = 0.f, s2 = 0.f;
    for (int i = 0; i < kHD2; ++i) { s1 += lq1[i] * lk1[i]; s2 += lq2[i] * lk2[i]; }
    const float lam = __expf(s1) - __expf(s2) + kLambdaInit;

    for (int c = tid; c < 256 * 34; c += 256) {
        int row = c / 34, s4 = (c - row * 34) * 4;
        uint2 val = make_uint2(0u, 0u);
        const bf16* kg = qkv + (tokbase + row) * kQKV + kE + h * 72;
        if (s4 < 36)                    val = *(const uint2*)(kg + s4);
        else if (s4 >= 64 && s4 < 100)  val = *(const uint2*)(kg + s4 - 28);
        *(uint2*)(Kp + row * 136 + s4) = val;
    }
    for (int c = tid; c < 256 * 18; c += 256) {
        int j = c / 18, s4 = (c - j * 18) * 4;
        union { uint2 u; unsigned short e[4]; } uu;
        uu.u = *(const uint2*)(qkv + (tokbase + j) * kQKV + 2 * kE + h * 72 + s4);
#pragma unroll
        for (int x = 0; x < 4; ++x)
            ((unsigned short*)VT)[(s4 + x) * 264 + j] = uu.e[x];
    }
    for (int c = tid; c < 8 * 256; c += 256) {
        int d = 72 + (c >> 8), j = c & 255;
        ((unsigned short*)VT)[d * 264 + j] = 0;
    }
    __syncthreads();

    const int w = tid >> 6, lane = tid & 63, quad = lane >> 4, l16 = lane & 15;
    bf16* Pw = Pb + w * (16 * 264);
    const float sc = 0.117851130f;            // 1/sqrt(72)
    const float oscale = 1.f - kLambdaInit;

    float sw[5];
#pragma unroll
    for (int dt = 0; dt < 5; ++dt) {
        int d = dt * 16 + l16;
        sw[dt] = (d < 72) ? subln_w[d] : 0.f;
    }

    for (int s = 0; s < 4; ++s) {
        const int q0 = w * 64 + s * 16;
        const bf16* qg = qkv + (tokbase + q0 + l16) * kQKV + h * 72;
        U8 qe0, qe1, qo0, qo1;
        qe0.u4 = *(const uint4*)(qg + quad * 8);
        qe1.u4 = *(const uint4*)(qg + 32);
        qo0.u2[0] = *(const uint2*)(qg + 36 + quad * 8);
        qo0.u2[1] = *(const uint2*)(qg + 40 + quad * 8);
        qo1.u2[0] = *(const uint2*)(qg + 68);
        qo1.u2[1] = *(const uint2*)(qg + 72);
#pragma unroll
        for (int j = 0; j < 8; ++j) {
            bool keep = (quad == 0) && (j < 4);
            if (!keep) { qe1.e[j] = 0; qo1.e[j] = 0; }
        }

        f32x4 se[16], so[16];
#pragma unroll
        for (int t = 0; t < 16; ++t) { se[t] = f32x4{0,0,0,0}; so[t] = f32x4{0,0,0,0}; }
#pragma unroll
        for (int t = 0; t < 16; ++t) {
            const bf16* kr = Kp + (t * 16 + l16) * 136;
            bf16x8 ke0 = *(const bf16x8*)(kr + quad * 8);
            bf16x8 ke1 = *(const bf16x8*)(kr + 32 + quad * 8);
            bf16x8 ko0 = *(const bf16x8*)(kr + 64 + quad * 8);
            bf16x8 ko1 = *(const bf16x8*)(kr + 96 + quad * 8);
            se[t] = __builtin_amdgcn_mfma_f32_16x16x32_bf16(qe0.v, ke0, se[t], 0, 0, 0);
            se[t] = __builtin_amdgcn_mfma_f32_16x16x32_bf16(qe1.v, ke1, se[t], 0, 0, 0);
            so[t] = __builtin_amdgcn_mfma_f32_16x16x32_bf16(qo0.v, ko0, so[t], 0, 0, 0);
            so[t] = __builtin_amdgcn_mfma_f32_16x16x32_bf16(qo1.v, ko1, so[t], 0, 0, 0);
        }

#pragma unroll
        for (int reg = 0; reg < 4; ++reg) {
            float me = -1e30f, mo = -1e30f;
#pragma unroll
            for (int t = 0; t < 16; ++t) {
                me = fmaxf(me, se[t][reg]);
                mo = fmaxf(mo, so[t][reg]);
            }
#pragma unroll
            for (int m = 1; m < 16; m <<= 1) {
                me = fmaxf(me, __shfl_xor(me, m, 64));
                mo = fmaxf(mo, __shfl_xor(mo, m, 64));
            }
            float sume = 0.f, sumo = 0.f;
#pragma unroll
            for (int t = 0; t < 16; ++t) {
                float pe = __expf((se[t][reg] - me) * sc);
                float po = __expf((so[t][reg] - mo) * sc);
                se[t][reg] = pe; sume += pe;
                so[t][reg] = po; sumo += po;
            }
#pragma unroll
            for (int m = 1; m < 16; m <<= 1) {
                sume += __shfl_xor(sume, m, 64);
                sumo += __shfl_xor(sumo, m, 64);
            }
            const float ie = 1.f / sume, io = lam / sumo;
            bf16* prow = Pw + (quad * 4 + reg) * 264;
#pragma unroll
            for (int t = 0; t < 16; ++t) {
                float p = se[t][reg] * ie - so[t][reg] * io;
                prow[t * 16 + l16] = __float2bfloat16(p);
            }
        }

        f32x4 oacc[5];
#pragma unroll
        for (int dt = 0; dt < 5; ++dt) oacc[dt] = f32x4{0,0,0,0};
#pragma unroll
        for (int k0 = 0; k0 < 256; k0 += 32) {
            bf16x8 pf = *(const bf16x8*)(Pw + l16 * 264 + k0 + quad * 8);
#pragma unroll
            for (int dt = 0; dt < 5; ++dt) {
                bf16x8 vf = *(const bf16x8*)(VT + (dt * 16 + l16) * 264 + k0 + quad * 8);
                oacc[dt] = __builtin_amdgcn_mfma_f32_16x16x32_bf16(pf, vf, oacc[dt], 0, 0, 0);
            }
        }

#pragma unroll
        for (int reg = 0; reg < 4; ++reg) {
            float ssq = 0.f;
#pragma unroll
            for (int dt = 0; dt < 5; ++dt) {
                float v = oacc[dt][reg];
                if (dt < 4 || l16 < 8) ssq += v * v;
            }
#pragma unroll
            for (int m = 1; m < 16; m <<= 1) ssq += __shfl_xor(ssq, m, 64);
            float scale = rsqrtf(ssq * (1.f / 72.f) + kSublnEps) * oscale;
            size_t orow = (tokbase + q0 + quad * 4 + reg) * (size_t)kE + h * 72;
#pragma unroll
            for (int dt = 0; dt < 5; ++dt) {
                int d = dt * 16 + l16;
                if (d < 72)
                    out[orow + d] = __float2bfloat16(oacc[dt][reg] * scale * sw[dt]);
            }
        }
    }
}

// ---------------- launch ----------------
extern "C" void kernel_launch(void* const* d_in, const int* in_sizes, int n_in,
                              void* d_out, int out_size, void* d_ws, size_t ws_size,
                              hipStream_t stream)
{
    const float* hidden = (const float*)d_in[0];
    const float* Wq = (const float*)d_in[1];
    const float* bq = (const float*)d_in[2];
    const float* Wk = (const float*)d_in[3];
    const float* bk = (const float*)d_in[4];
    const float* Wv = (const float*)d_in[5];
    const float* bv = (const float*)d_in[6];
    const float* Wo = (const float*)d_in[7];
    const float* bo = (const float*)d_in[8];
    const float* lq1 = (const float*)d_in[9];
    const float* lk1 = (const float*)d_in[10];
    const float* lq2 = (const float*)d_in[11];
    const float* lk2 = (const float*)d_in[12];
    const float* subln_w = (const float*)d_in[13];
    const float* rms1_w = (const float*)d_in[14];
    const float* rms2_w = (const float*)d_in[15];
    const float* fc1_w = (const float*)d_in[16];
    const float* fc1_b = (const float*)d_in[17];
    const float* fc2_w = (const float*)d_in[18];
    const float* fc2_b = (const float*)d_in[19];
    float* outp = (float*)d_out;

    char* wsp = (char*)d_ws;
    size_t off = 0;
    auto alloc = [&](size_t bytes) {
        char* p = wsp + off;
        off += (bytes + 255) & ~(size_t)255;
        return p;
    };
    bf16* wqkv = (bf16*)alloc((size_t)kQKV * kE * 2);
    bf16* wo   = (bf16*)alloc((size_t)kE * kE * 2);
    bf16* w1   = (bf16*)alloc((size_t)kFFP * kE * 2);
    bf16* w2   = (bf16*)alloc((size_t)kE * kFFP * 2);
    float* bqkv = (float*)alloc((size_t)kQKV * 4);
    float* b1   = (float*)alloc((size_t)kFFP * 4);
    bf16* xb    = (bf16*)alloc((size_t)kT * kE * 2);
    bf16* big   = (bf16*)alloc((size_t)kT * kFFP * 2);
    (void)ws_size;

    convert_all<<<(int)((kCvtTotal / 4 + 255) / 256), 256, 0, stream>>>(
        Wq, Wk, Wv, Wo, fc1_w, fc2_w, wqkv, wo, w1, w2);
    prep_bias<<<17, 256, 0, stream>>>(bq, bk, bv, fc1_b, bqkv, b1);

    rmsnorm_kernel<<<kT, 256, 0, stream>>>(hidden, rms1_w, xb, kRmsEps);
    // qkv projection: [8192,1152] x [3456,1152]^T -> big [8192,3456] bf16
    gemm128<0><<<dim3(kQKV / 64, kT / 128), 256, 0, stream>>>(
        xb, wqkv, bqkv, nullptr, big, kQKV, kE, kE);
    attn_mfma<<<kB * kH, 256, 0, stream>>>(
        big, lq1, lk1, lq2, lk2, subln_w, xb);
    // h = attn @ Wo^T + bo + hidden -> d_out (fp32), N=1152 exact
    gemm128<2><<<dim3(kE / 64, kT / 128), 256, 0, stream>>>(
        xb, wo, bo, hidden, d_out, kE, kE, kE);
    rmsnorm_kernel<<<kT, 256, 0, stream>>>(outp, rms2_w, xb, kRmsEps);
    gemm128<1><<<dim3(kFFP / 64, kT / 128), 256, 0, stream>>>(
        xb, w1, b1, nullptr, big, kFFP, kE, kE);
    // fc2: [8192,4352] x [1152,4352]^T; += h (in d_out) + bias -> d_out
    gemm128<2><<<dim3(kE / 64, kT / 128), 256, 0, stream>>>(
        big, w2, fc2_b, outp, d_out, kE, kFFP, kFFP);
}

// Round 7
// 642.002 us; speedup vs baseline: 1.0749x; 1.0116x over previous
//
#include <hip/hip_runtime.h>
#include <hip/hip_bf16.h>

typedef __hip_bfloat16 bf16;
typedef __attribute__((ext_vector_type(4))) float f32x4;
typedef __attribute__((ext_vector_type(8))) __bf16 bf16x8;

constexpr int kE   = 1152;
constexpr int kH   = 16;
constexpr int kHD2 = 36;
constexpr int kFF  = 4304;
constexpr int kFFP = 4352;   // padded to 68*64
constexpr int kB   = 32;
constexpr int kS   = 256;
constexpr int kT   = kB * kS;      // 8192 tokens
constexpr int kQKV = 3456;         // 3*E (54*64, exact)
constexpr float kLambdaInit = 0.7778701f;   // 0.8 - 0.6*exp(-0.3*11)
constexpr float kRmsEps = 1e-6f;
constexpr float kSublnEps = 1e-5f;

__device__ inline void async_copy16(const void* gsrc, void* ldst) {
    __builtin_amdgcn_global_load_lds(
        (__attribute__((address_space(1))) void*)gsrc,
        (__attribute__((address_space(3))) void*)ldst, 16, 0, 0);
}

// ---------------- fused weight convert / pad, 4 elems/thread ----------------
constexpr int  kNEE  = kE * kE;                        // 1327104
constexpr long kSeg0 = 3L * kNEE;                      // wqkv [3456][1152]
constexpr long kSeg1 = kSeg0 + kNEE;                   // wo   [1152][1152]
constexpr long kSeg2 = kSeg1 + (long)kFFP * kE;        // w1   [4352][1152]
constexpr long kCvtTotal = kSeg2 + (long)kE * kFFP;    // w2   [1152][4352]

__global__ __launch_bounds__(256) void convert_all(
    const float* __restrict__ Wq, const float* __restrict__ Wk,
    const float* __restrict__ Wv, const float* __restrict__ Wo,
    const float* __restrict__ f1, const float* __restrict__ f2,
    bf16* __restrict__ wqkv, bf16* __restrict__ wo,
    bf16* __restrict__ w1, bf16* __restrict__ w2)
{
    long i = ((long)blockIdx.x * 256 + threadIdx.x) * 4;
    if (i >= kCvtTotal) return;
    float4 v = make_float4(0.f, 0.f, 0.f, 0.f);
    bf16* dst;
    if (i < kSeg0) {                       // wqkv, exact (no pad)
        long j = i;
        const float* src = (j < kNEE) ? Wq : (j < 2L * kNEE) ? Wk : Wv;
        v = *(const float4*)(src + (j % kNEE));
        dst = wqkv + j;
    } else if (i < kSeg1) {                // wo, exact
        long j = i - kSeg0;
        v = *(const float4*)(Wo + j);
        dst = wo + j;
    } else if (i < kSeg2) {                // w1 [4352][1152], rows>=4304 zero
        long j = i - kSeg1;
        if (j < (long)kFF * kE) v = *(const float4*)(f1 + j);
        dst = w1 + j;
    } else {                               // w2 [1152][4352], cols>=4304 zero
        long j = i - kSeg2;
        int n = (int)(j / kFFP), k = (int)(j - (long)n * kFFP);
        if (k < kFF) v = *(const float4*)(f2 + (long)n * kFF + k);
        dst = w2 + j;
    }
    union { uint2 u; bf16 e[4]; } o;
    o.e[0] = __float2bfloat16(v.x); o.e[1] = __float2bfloat16(v.y);
    o.e[2] = __float2bfloat16(v.z); o.e[3] = __float2bfloat16(v.w);
    *(uint2*)dst = o.u;
}

__global__ __launch_bounds__(256) void prep_bias(
    const float* __restrict__ bq, const float* __restrict__ bk,
    const float* __restrict__ bv, const float* __restrict__ fb,
    float* __restrict__ bqkv, float* __restrict__ fbp)
{
    int i = blockIdx.x * 256 + threadIdx.x;
    if (i < kQKV) {
        float v = (i < kE) ? bq[i] : (i < 2 * kE) ? bk[i - kE] : bv[i - 2 * kE];
        bqkv[i] = v;
    }
    if (i < kFFP) fbp[i] = (i < kFF) ? fb[i] : 0.f;
}

// ---------------- RMSNorm (fp32 in -> bf16 out) ----------------
__global__ __launch_bounds__(256) void rmsnorm_kernel(
    const float* __restrict__ x, const float* __restrict__ w,
    bf16* __restrict__ out, float eps)
{
    int row = blockIdx.x;
    const float* xr = x + (size_t)row * kE;
    float vals[5];
    float ss = 0.f;
    int n = 0;
    for (int j = threadIdx.x; j < kE; j += 256) {
        float v = xr[j];
        vals[n++] = v;
        ss += v * v;
    }
    for (int m = 32; m > 0; m >>= 1) ss += __shfl_xor(ss, m, 64);
    __shared__ float red[4];
    if ((threadIdx.x & 63) == 0) red[threadIdx.x >> 6] = ss;
    __syncthreads();
    float tot = red[0] + red[1] + red[2] + red[3];
    float scale = rsqrtf(tot / (float)kE + eps);
    n = 0;
    for (int j = threadIdx.x; j < kE; j += 256)
        out[(size_t)row * kE + j] = __float2bfloat16(vals[n++] * scale * w[j]);
}

// ---- bf16 NT GEMM, 128Mx64N tile, BK=64, 4 waves, dbuf, 3 blocks/CU ----
// A [M,ldk] bf16 row-major, Bw [N,ldk] bf16 row-major (N mult of 64).
// EPI: 0 bf16+bias | 1 gelu bf16+bias | 2 fp32+bias+add.
// 48 KiB LDS (128B rows: conflict-free swizzle) -> 3 blocks/CU TLP;
// counted vmcnt(6) mid-loop (6 gload_lds per tile: 4 A + 2 B).
#define GBAR() do { asm volatile("" ::: "memory"); \
                    __builtin_amdgcn_s_barrier();  \
                    asm volatile("" ::: "memory"); } while (0)

template <int EPI>
__global__ __launch_bounds__(256, 3) void gemm128(
    const bf16* __restrict__ A, const bf16* __restrict__ Bw,
    const float* __restrict__ bias, const float* add, void* out,
    int N, int K, int ldk)
{
    // [parity]: A 128 rows x 128B at 0, B 64 rows x 128B at 16384
    __shared__ __align__(16) char sm[2][24576];

    const int tid  = threadIdx.x;
    const int lane = tid & 63;
    const int wave = tid >> 6;
    const int wm   = wave >> 1;        // 0,1: M-half (64 rows)
    const int wn   = wave & 1;         // 0,1: N-half (32 cols)
    const int q4   = lane >> 4;
    const int l16  = lane & 15;

    // XCD-strip locality map (gridDim.y == 64 == 8 XCDs x 8 bm rows):
    // XCD x owns bm in [8x, 8x+8); within the strip bm varies FASTEST, so the
    // ~96 concurrent blocks/XCD touch 8 A-panels (2.4 MB, L2-resident) while
    // streaming B columns; all XCDs read the same B column together (L3-hit).
    // Bijective: orig = (bn*8 + (bm&7))*8 + xcd.
    const int orig = blockIdx.y * gridDim.x + blockIdx.x;
    const int xcd  = orig & 7;
    const int loc  = orig >> 3;
    const int bm   = xcd * 8 + (loc & 7);
    const int bn   = loc >> 3;

    const int NT = K >> 6;

    // staging: linear LDS dest (gload_lds constraint), pre-swizzled global col.
    // LDS[row][slot] holds global (row, slot ^ (row&7)); 16B slots, 8 per row.
    const int trow = tid >> 3;                               // 0..31
    const int tswz = ((tid & 7) ^ (trow & 7)) << 4;
    const size_t rs = (size_t)ldk * 2;
    const char* aG = (const char*)A + (size_t)(bm * 128 + trow) * rs + tswz;
    const char* bG = (const char*)Bw + (size_t)(bn * 64 + trow) * rs + tswz;

#define STAGE(par, tt)                                                          \
    {                                                                           \
        const size_t kb = (size_t)(tt) * 128;                                   \
        async_copy16(aG + kb,           sm[par] + tid * 16);                    \
        async_copy16(aG + 32 * rs + kb, sm[par] + tid * 16 + 4096);             \
        async_copy16(aG + 64 * rs + kb, sm[par] + tid * 16 + 8192);             \
        async_copy16(aG + 96 * rs + kb, sm[par] + tid * 16 + 12288);            \
        async_copy16(bG + kb,           sm[par] + tid * 16 + 16384);            \
        async_copy16(bG + 32 * rs + kb, sm[par] + tid * 16 + 20480);            \
    }

    // per-lane ds_read offsets (swizzle-matched; rows == l16 mod 8)
    int aoff[2], boff[2];
#pragma unroll
    for (int kh = 0; kh < 2; ++kh) {
        const int sw = (((kh << 2) + q4) ^ (l16 & 7)) << 4;
        aoff[kh] = (wm * 64 + l16) * 128 + sw;
        boff[kh] = 16384 + (wn * 32 + l16) * 128 + sw;
    }

    f32x4 acc[4][2] = {};
    bf16x8 afr[4][2], bfr[2][2];

    // prologue: tiles 0,1 staged into par 0,1; wait tile 0 (6 newest in flight)
    STAGE(0, 0);
    if (NT > 1) {
        STAGE(1, 1);
        asm volatile("s_waitcnt vmcnt(6)" ::: "memory");
    } else {
        asm volatile("s_waitcnt vmcnt(0)" ::: "memory");
    }
    GBAR();

    for (int t = 0; t < NT; ++t) {
        const int par = t & 1;
        const char* sB0 = sm[par];

        // read all fragments for this K-tile (12 x ds_read_b128)
#pragma unroll
        for (int mi = 0; mi < 4; ++mi)
#pragma unroll
            for (int kh = 0; kh < 2; ++kh)
                afr[mi][kh] = *(const bf16x8*)(sB0 + mi * 2048 + aoff[kh]);
#pragma unroll
        for (int ni = 0; ni < 2; ++ni)
#pragma unroll
            for (int kh = 0; kh < 2; ++kh)
                bfr[ni][kh] = *(const bf16x8*)(sB0 + ni * 2048 + boff[kh]);
        // drain my reads so the barrier certifies buffer[par] fully consumed
        asm volatile("s_waitcnt lgkmcnt(0)" ::: "memory");
        GBAR();

        // stage t+2 into this (now consumed) buffer; runs under the MFMAs
        if (t + 2 < NT) STAGE(par, t + 2);
        __builtin_amdgcn_s_setprio(1);
#pragma unroll
        for (int mi = 0; mi < 4; ++mi)
#pragma unroll
            for (int ni = 0; ni < 2; ++ni)
#pragma unroll
                for (int kh = 0; kh < 2; ++kh)
                    acc[mi][ni] = __builtin_amdgcn_mfma_f32_16x16x32_bf16(
                        afr[mi][kh], bfr[ni][kh], acc[mi][ni], 0, 0, 0);
        __builtin_amdgcn_s_setprio(0);
        if (t + 2 < NT) {
            // outstanding: tile t+1 (6) + tile t+2 (6); drain oldest 6
            asm volatile("s_waitcnt vmcnt(6)" ::: "memory");
        } else {
            asm volatile("s_waitcnt vmcnt(0)" ::: "memory");
        }
        GBAR();
    }
#undef STAGE

    // ---- epilogue: per-wave 64x32 at (wm,wn) ----
    const int growb = bm * 128 + wm * 64;
    const int gcolb = bn * 64 + wn * 32;
#pragma unroll
    for (int mi = 0; mi < 4; ++mi) {
#pragma unroll
        for (int ni = 0; ni < 2; ++ni) {
            const int gcol = gcolb + ni * 16 + l16;
            const float bv = bias[gcol];
#pragma unroll
            for (int r = 0; r < 4; ++r) {
                const int grow = growb + mi * 16 + q4 * 4 + r;
                float v = acc[mi][ni][r] + bv;
                size_t idx = (size_t)grow * N + gcol;
                if (EPI == 0) {
                    ((bf16*)out)[idx] = __float2bfloat16(v);
                } else if (EPI == 1) {
                    float u = 1.5957691216f * (v + 0.044715f * v * v * v);
                    float g = v / (1.f + __expf(-u));
                    ((bf16*)out)[idx] = __float2bfloat16(g);
                } else {
                    ((float*)out)[idx] = v + add[idx];
                }
            }
        }
    }
}

// ---------------- MFMA differential attention + subln ----------------
union U8 { bf16x8 v; uint4 u4; uint2 u2[2]; unsigned short e[8]; };

__global__ __launch_bounds__(256) void attn_mfma(
    const bf16* __restrict__ qkv,
    const float* __restrict__ lq1, const float* __restrict__ lk1,
    const float* __restrict__ lq2, const float* __restrict__ lk2,
    const float* __restrict__ subln_w, bf16* __restrict__ out)
{
    __shared__ __align__(16) bf16 Kp[256 * 136];   // 69632 B
    __shared__ __align__(16) bf16 VT[80 * 264];    // 42240 B
    __shared__ __align__(16) bf16 Pb[4 * 16 * 264];// 33792 B   (total 145664)

    const int tid = threadIdx.x;
    const int h = blockIdx.x & 15;
    const int b = blockIdx.x >> 4;
    const size_t tokbase = (size_t)b * kS;

    float s1 = 0.f, s2 = 0.f;
    for (int i = 0; i < kHD2; ++i) { s1 += lq1[i] * lk1[i]; s2 += lq2[i] * lk2[i]; }
    const float lam = __expf(s1) - __expf(s2) + kLambdaInit;

    for (int c = tid; c < 256 * 34; c += 256) {
        int row = c / 34, s4 = (c - row * 34) * 4;
        uint2 val = make_uint2(0u, 0u);
        const bf16* kg = qkv + (tokbase + row) * kQKV + kE + h * 72;
        if (s4 < 36)                    val = *(const uint2*)(kg + s4);
        else if (s4 >= 64 && s4 < 100)  val = *(const uint2*)(kg + s4 - 28);
        *(uint2*)(Kp + row * 136 + s4) = val;
    }
    for (int c = tid; c < 256 * 18; c += 256) {
        int j = c / 18, s4 = (c - j * 18) * 4;
        union { uint2 u; unsigned short e[4]; } uu;
        uu.u = *(const uint2*)(qkv + (tokbase + j) * kQKV + 2 * kE + h * 72 + s4);
#pragma unroll
        for (int x = 0; x < 4; ++x)
            ((unsigned short*)VT)[(s4 + x) * 264 + j] = uu.e[x];
    }
    for (int c = tid; c < 8 * 256; c += 256) {
        int d = 72 + (c >> 8), j = c & 255;
        ((unsigned short*)VT)[d * 264 + j] = 0;
    }
    __syncthreads();

    const int w = tid >> 6, lane = tid & 63, quad = lane >> 4, l16 = lane & 15;
    bf16* Pw = Pb + w * (16 * 264);
    const float sc = 0.117851130f;            // 1/sqrt(72)
    const float oscale = 1.f - kLambdaInit;

    float sw[5];
#pragma unroll
    for (int dt = 0; dt < 5; ++dt) {
        int d = dt * 16 + l16;
        sw[dt] = (d < 72) ? subln_w[d] : 0.f;
    }

    for (int s = 0; s < 4; ++s) {
        const int q0 = w * 64 + s * 16;
        const bf16* qg = qkv + (tokbase + q0 + l16) * kQKV + h * 72;
        U8 qe0, qe1, qo0, qo1;
        qe0.u4 = *(const uint4*)(qg + quad * 8);
        qe1.u4 = *(const uint4*)(qg + 32);
        qo0.u2[0] = *(const uint2*)(qg + 36 + quad * 8);
        qo0.u2[1] = *(const uint2*)(qg + 40 + quad * 8);
        qo1.u2[0] = *(const uint2*)(qg + 68);
        qo1.u2[1] = *(const uint2*)(qg + 72);
#pragma unroll
        for (int j = 0; j < 8; ++j) {
            bool keep = (quad == 0) && (j < 4);
            if (!keep) { qe1.e[j] = 0; qo1.e[j] = 0; }
        }

        f32x4 se[16], so[16];
#pragma unroll
        for (int t = 0; t < 16; ++t) { se[t] = f32x4{0,0,0,0}; so[t] = f32x4{0,0,0,0}; }
#pragma unroll
        for (int t = 0; t < 16; ++t) {
            const bf16* kr = Kp + (t * 16 + l16) * 136;
            bf16x8 ke0 = *(const bf16x8*)(kr + quad * 8);
            bf16x8 ke1 = *(const bf16x8*)(kr + 32 + quad * 8);
            bf16x8 ko0 = *(const bf16x8*)(kr + 64 + quad * 8);
            bf16x8 ko1 = *(const bf16x8*)(kr + 96 + quad * 8);
            se[t] = __builtin_amdgcn_mfma_f32_16x16x32_bf16(qe0.v, ke0, se[t], 0, 0, 0);
            se[t] = __builtin_amdgcn_mfma_f32_16x16x32_bf16(qe1.v, ke1, se[t], 0, 0, 0);
            so[t] = __builtin_amdgcn_mfma_f32_16x16x32_bf16(qo0.v, ko0, so[t], 0, 0, 0);
            so[t] = __builtin_amdgcn_mfma_f32_16x16x32_bf16(qo1.v, ko1, so[t], 0, 0, 0);
        }

#pragma unroll
        for (int reg = 0; reg < 4; ++reg) {
            float me = -1e30f, mo = -1e30f;
#pragma unroll
            for (int t = 0; t < 16; ++t) {
                me = fmaxf(me, se[t][reg]);
                mo = fmaxf(mo, so[t][reg]);
            }
#pragma unroll
            for (int m = 1; m < 16; m <<= 1) {
                me = fmaxf(me, __shfl_xor(me, m, 64));
                mo = fmaxf(mo, __shfl_xor(mo, m, 64));
            }
            float sume = 0.f, sumo = 0.f;
#pragma unroll
            for (int t = 0; t < 16; ++t) {
                float pe = __expf((se[t][reg] - me) * sc);
                float po = __expf((so[t][reg] - mo) * sc);
                se[t][reg] = pe; sume += pe;
                so[t][reg] = po; sumo += po;
            }
#pragma unroll
            for (int m = 1; m < 16; m <<= 1) {
                sume += __shfl_xor(sume, m, 64);
                sumo += __shfl_xor(sumo, m, 64);
            }
            const float ie = 1.f / sume, io = lam / sumo;
            bf16* prow = Pw + (quad * 4 + reg) * 264;
#pragma unroll
            for (int t = 0; t < 16; ++t) {
                float p = se[t][reg] * ie - so[t][reg] * io;
                prow[t * 16 + l16] = __float2bfloat16(p);
            }
        }

        f32x4 oacc[5];
#pragma unroll
        for (int dt = 0; dt < 5; ++dt) oacc[dt] = f32x4{0,0,0,0};
#pragma unroll
        for (int k0 = 0; k0 < 256; k0 += 32) {
            bf16x8 pf = *(const bf16x8*)(Pw + l16 * 264 + k0 + quad * 8);
#pragma unroll
            for (int dt = 0; dt < 5; ++dt) {
                bf16x8 vf = *(const bf16x8*)(VT + (dt * 16 + l16) * 264 + k0 + quad * 8);
                oacc[dt] = __builtin_amdgcn_mfma_f32_16x16x32_bf16(pf, vf, oacc[dt], 0, 0, 0);
            }
        }

#pragma unroll
        for (int reg = 0; reg < 4; ++reg) {
            float ssq = 0.f;
#pragma unroll
            for (int dt = 0; dt < 5; ++dt) {
                float v = oacc[dt][reg];
                if (dt < 4 || l16 < 8) ssq += v * v;
            }
#pragma unroll
            for (int m = 1; m < 16; m <<= 1) ssq += __shfl_xor(ssq, m, 64);
            float scale = rsqrtf(ssq * (1.f / 72.f) + kSublnEps) * oscale;
            size_t orow = (tokbase + q0 + quad * 4 + reg) * (size_t)kE + h * 72;
#pragma unroll
            for (int dt = 0; dt < 5; ++dt) {
                int d = dt * 16 + l16;
                if (d < 72)
                    out[orow + d] = __float2bfloat16(oacc[dt][reg] * scale * sw[dt]);
            }
        }
    }
}

// ---------------- launch ----------------
extern "C" void kernel_launch(void* const* d_in, const int* in_sizes, int n_in,
                              void* d_out, int out_size, void* d_ws, size_t ws_size,
                              hipStream_t stream)
{
    const float* hidden = (const float*)d_in[0];
    const float* Wq = (const float*)d_in[1];
    const float* bq = (const float*)d_in[2];
    const float* Wk = (const float*)d_in[3];
    const float* bk = (const float*)d_in[4];
    const float* Wv = (const float*)d_in[5];
    const float* bv = (const float*)d_in[6];
    const float* Wo = (const float*)d_in[7];
    const float* bo = (const float*)d_in[8];
    const float* lq1 = (const float*)d_in[9];
    const float* lk1 = (const float*)d_in[10];
    const float* lq2 = (const float*)d_in[11];
    const float* lk2 = (const float*)d_in[12];
    const float* subln_w = (const float*)d_in[13];
    const float* rms1_w = (const float*)d_in[14];
    const float* rms2_w = (const float*)d_in[15];
    const float* fc1_w = (const float*)d_in[16];
    const float* fc1_b = (const float*)d_in[17];
    const float* fc2_w = (const float*)d_in[18];
    const float* fc2_b = (const float*)d_in[19];
    float* outp = (float*)d_out;

    char* wsp = (char*)d_ws;
    size_t off = 0;
    auto alloc = [&](size_t bytes) {
        char* p = wsp + off;
        off += (bytes + 255) & ~(size_t)255;
        return p;
    };
    bf16* wqkv = (bf16*)alloc((size_t)kQKV * kE * 2);
    bf16* wo   = (bf16*)alloc((size_t)kE * kE * 2);
    bf16* w1   = (bf16*)alloc((size_t)kFFP * kE * 2);
    bf16* w2   = (bf16*)alloc((size_t)kE * kFFP * 2);
    float* bqkv = (float*)alloc((size_t)kQKV * 4);
    float* b1   = (float*)alloc((size_t)kFFP * 4);
    bf16* xb    = (bf16*)alloc((size_t)kT * kE * 2);
    bf16* big   = (bf16*)alloc((size_t)kT * kFFP * 2);
    (void)ws_size;

    convert_all<<<(int)((kCvtTotal / 4 + 255) / 256), 256, 0, stream>>>(
        Wq, Wk, Wv, Wo, fc1_w, fc2_w, wqkv, wo, w1, w2);
    prep_bias<<<17, 256, 0, stream>>>(bq, bk, bv, fc1_b, bqkv, b1);

    rmsnorm_kernel<<<kT, 256, 0, stream>>>(hidden, rms1_w, xb, kRmsEps);
    // qkv projection: [8192,1152] x [3456,1152]^T -> big [8192,3456] bf16
    gemm128<0><<<dim3(kQKV / 64, kT / 128), 256, 0, stream>>>(
        xb, wqkv, bqkv, nullptr, big, kQKV, kE, kE);
    attn_mfma<<<kB * kH, 256, 0, stream>>>(
        big, lq1, lk1, lq2, lk2, subln_w, xb);
    // h = attn @ Wo^T + bo + hidden -> d_out (fp32), N=1152 exact
    gemm128<2><<<dim3(kE / 64, kT / 128), 256, 0, stream>>>(
        xb, wo, bo, hidden, d_out, kE, kE, kE);
    rmsnorm_kernel<<<kT, 256, 0, stream>>>(outp, rms2_w, xb, kRmsEps);
    gemm128<1><<<dim3(kFFP / 64, kT / 128), 256, 0, stream>>>(
        xb, w1, b1, nullptr, big, kFFP, kE, kE);
    // fc2: [8192,4352] x [1152,4352]^T; += h (in d_out) + bias -> d_out
    gemm128<2><<<dim3(kE / 64, kT / 128), 256, 0, stream>>>(
        big, w2, fc2_b, outp, d_out, kE, kFFP, kFFP);
}

// Round 8
// 616.700 us; speedup vs baseline: 1.1190x; 1.0410x over previous
//
#include <hip/hip_runtime.h>
#include <hip/hip_bf16.h>

typedef __hip_bfloat16 bf16;
typedef __attribute__((ext_vector_type(4))) float f32x4;
typedef __attribute__((ext_vector_type(8))) __bf16 bf16x8;

constexpr int kE   = 1152;
constexpr int kH   = 16;
constexpr int kHD2 = 36;
constexpr int kFF  = 4304;
constexpr int kFFP = 4352;   // padded to 34*128
constexpr int kB   = 32;
constexpr int kS   = 256;
constexpr int kT   = kB * kS;      // 8192 tokens
constexpr int kQKV = 3456;         // 3*E (27*128, exact)
constexpr float kLambdaInit = 0.7778701f;   // 0.8 - 0.6*exp(-0.3*11)
constexpr float kRmsEps = 1e-6f;
constexpr float kSublnEps = 1e-5f;

__device__ inline void async_copy16(const void* gsrc, void* ldst) {
    __builtin_amdgcn_global_load_lds(
        (__attribute__((address_space(1))) void*)gsrc,
        (__attribute__((address_space(3))) void*)ldst, 16, 0, 0);
}

// ---------------- fused weight convert / pad, 4 elems/thread ----------------
constexpr int  kNEE  = kE * kE;                        // 1327104
constexpr long kSeg0 = 3L * kNEE;                      // wqkv [3456][1152]
constexpr long kSeg1 = kSeg0 + kNEE;                   // wo   [1152][1152]
constexpr long kSeg2 = kSeg1 + (long)kFFP * kE;        // w1   [4352][1152]
constexpr long kCvtTotal = kSeg2 + (long)kE * kFFP;    // w2   [1152][4352]

__global__ __launch_bounds__(256) void convert_all(
    const float* __restrict__ Wq, const float* __restrict__ Wk,
    const float* __restrict__ Wv, const float* __restrict__ Wo,
    const float* __restrict__ f1, const float* __restrict__ f2,
    bf16* __restrict__ wqkv, bf16* __restrict__ wo,
    bf16* __restrict__ w1, bf16* __restrict__ w2)
{
    long i = ((long)blockIdx.x * 256 + threadIdx.x) * 4;
    if (i >= kCvtTotal) return;
    float4 v = make_float4(0.f, 0.f, 0.f, 0.f);
    bf16* dst;
    if (i < kSeg0) {                       // wqkv, exact (no pad)
        long j = i;
        const float* src = (j < kNEE) ? Wq : (j < 2L * kNEE) ? Wk : Wv;
        v = *(const float4*)(src + (j % kNEE));
        dst = wqkv + j;
    } else if (i < kSeg1) {                // wo, exact
        long j = i - kSeg0;
        v = *(const float4*)(Wo + j);
        dst = wo + j;
    } else if (i < kSeg2) {                // w1 [4352][1152], rows>=4304 zero
        long j = i - kSeg1;
        if (j < (long)kFF * kE) v = *(const float4*)(f1 + j);
        dst = w1 + j;
    } else {                               // w2 [1152][4352], cols>=4304 zero
        long j = i - kSeg2;
        int n = (int)(j / kFFP), k = (int)(j - (long)n * kFFP);
        if (k < kFF) v = *(const float4*)(f2 + (long)n * kFF + k);
        dst = w2 + j;
    }
    union { uint2 u; bf16 e[4]; } o;
    o.e[0] = __float2bfloat16(v.x); o.e[1] = __float2bfloat16(v.y);
    o.e[2] = __float2bfloat16(v.z); o.e[3] = __float2bfloat16(v.w);
    *(uint2*)dst = o.u;
}

__global__ __launch_bounds__(256) void prep_bias(
    const float* __restrict__ bq, const float* __restrict__ bk,
    const float* __restrict__ bv, const float* __restrict__ fb,
    float* __restrict__ bqkv, float* __restrict__ fbp)
{
    int i = blockIdx.x * 256 + threadIdx.x;
    if (i < kQKV) {
        float v = (i < kE) ? bq[i] : (i < 2 * kE) ? bk[i - kE] : bv[i - 2 * kE];
        bqkv[i] = v;
    }
    if (i < kFFP) fbp[i] = (i < kFF) ? fb[i] : 0.f;
}

// ---------------- RMSNorm (fp32 in -> bf16 out) ----------------
__global__ __launch_bounds__(256) void rmsnorm_kernel(
    const float* __restrict__ x, const float* __restrict__ w,
    bf16* __restrict__ out, float eps)
{
    int row = blockIdx.x;
    const float* xr = x + (size_t)row * kE;
    float vals[5];
    float ss = 0.f;
    int n = 0;
    for (int j = threadIdx.x; j < kE; j += 256) {
        float v = xr[j];
        vals[n++] = v;
        ss += v * v;
    }
    for (int m = 32; m > 0; m >>= 1) ss += __shfl_xor(ss, m, 64);
    __shared__ float red[4];
    if ((threadIdx.x & 63) == 0) red[threadIdx.x >> 6] = ss;
    __syncthreads();
    float tot = red[0] + red[1] + red[2] + red[3];
    float scale = rsqrtf(tot / (float)kE + eps);
    n = 0;
    for (int j = threadIdx.x; j < kE; j += 256)
        out[(size_t)row * kE + j] = __float2bfloat16(vals[n++] * scale * w[j]);
}

// ---- bf16 NT GEMM, 128Mx128N tile, 64x64/wave, BK=64, 3 blocks/CU ----
// A [M,ldk] bf16 row-major, Bw [N,ldk] bf16 row-major (N mult of 128).
// EPI: 0 bf16+bias | 1 gelu bf16+bias | 2 fp32+bias+add.
// A single-buffered (16KB) + B double-buffered (32KB) = 48KB -> 3 blocks/CU,
// while the 64x64 wave tile halves LDS bytes/FLOP vs 64x32 (ceiling 30->44%).
// Counted vmcnt(4) mid-loop: drains B(t+1)+A(t+1), keeps B(t+2) in flight.
#define GBAR() do { asm volatile("" ::: "memory"); \
                    __builtin_amdgcn_s_barrier();  \
                    asm volatile("" ::: "memory"); } while (0)

template <int EPI>
__global__ __launch_bounds__(256, 3) void gemm128(
    const bf16* __restrict__ A, const bf16* __restrict__ Bw,
    const float* __restrict__ bias, const float* add, void* out,
    int N, int K, int ldk)
{
    // [A 128x128B][B par0 128x128B][B par1 128x128B]
    __shared__ __align__(16) char sm[49152];

    const int tid  = threadIdx.x;
    const int lane = tid & 63;
    const int wave = tid >> 6;
    const int wm   = wave >> 1;        // 0,1: M-half (64 rows)
    const int wn   = wave & 1;         // 0,1: N-half (64 cols)
    const int q4   = lane >> 4;
    const int l16  = lane & 15;

    // XCD-strip locality map (gridDim.y == 64 == 8 XCDs x 8 bm rows):
    // XCD x owns bm in [8x, 8x+8); bm varies fastest within the strip ->
    // 8 A-panels L2-resident per XCD, B columns streamed in lockstep (L3-hit).
    const int orig = blockIdx.y * gridDim.x + blockIdx.x;
    const int xcd  = orig & 7;
    const int loc  = orig >> 3;
    const int bm   = xcd * 8 + (loc & 7);
    const int bn   = loc >> 3;

    const int NT = K >> 6;

    // staging: linear LDS dest (gload_lds constraint), pre-swizzled global col.
    // LDS[row][slot] holds global (row, slot ^ (row&7)); 16B slots, 8 per row.
    const int trow = tid >> 3;                               // 0..31
    const int tswz = ((tid & 7) ^ (trow & 7)) << 4;
    const size_t rs = (size_t)ldk * 2;
    const char* aG = (const char*)A + (size_t)(bm * 128 + trow) * rs + tswz;
    const char* bG = (const char*)Bw + (size_t)(bn * 128 + trow) * rs + tswz;

#define STAGE_A(tt)                                                             \
    {                                                                           \
        const size_t kb = (size_t)(tt) * 128;                                   \
        async_copy16(aG + kb,           sm + tid * 16);                         \
        async_copy16(aG + 32 * rs + kb, sm + tid * 16 + 4096);                  \
        async_copy16(aG + 64 * rs + kb, sm + tid * 16 + 8192);                  \
        async_copy16(aG + 96 * rs + kb, sm + tid * 16 + 12288);                 \
    }
#define STAGE_B(par, tt)                                                        \
    {                                                                           \
        const size_t kb = (size_t)(tt) * 128;                                   \
        char* d = sm + 16384 + (par) * 16384 + tid * 16;                        \
        async_copy16(bG + kb,           d);                                     \
        async_copy16(bG + 32 * rs + kb, d + 4096);                              \
        async_copy16(bG + 64 * rs + kb, d + 8192);                              \
        async_copy16(bG + 96 * rs + kb, d + 12288);                             \
    }

    // per-lane ds_read offsets (swizzle-matched; rows == l16 mod 8)
    int aoff[2], boff[2];
#pragma unroll
    for (int kh = 0; kh < 2; ++kh) {
        const int sw = (((kh << 2) + q4) ^ (l16 & 7)) << 4;
        aoff[kh] = (wm * 64 + l16) * 128 + sw;
        boff[kh] = (wn * 64 + l16) * 128 + sw;
    }

    f32x4 acc[4][4] = {};
    bf16x8 afr[4][2], bfr[4][2];

    // prologue: A(0),B(0),B(1); wait A0+B0 (B1's 4 stay in flight)
    STAGE_A(0);
    STAGE_B(0, 0);
    if (NT > 1) {
        STAGE_B(1, 1);
        asm volatile("s_waitcnt vmcnt(4)" ::: "memory");
    } else {
        asm volatile("s_waitcnt vmcnt(0)" ::: "memory");
    }
    GBAR();

    for (int t = 0; t < NT; ++t) {
        const int par = t & 1;
        const char* sB = sm + 16384 + par * 16384;

        // read all fragments for this K-tile (16 x ds_read_b128)
#pragma unroll
        for (int mi = 0; mi < 4; ++mi)
#pragma unroll
            for (int kh = 0; kh < 2; ++kh)
                afr[mi][kh] = *(const bf16x8*)(sm + mi * 2048 + aoff[kh]);
#pragma unroll
        for (int ni = 0; ni < 4; ++ni)
#pragma unroll
            for (int kh = 0; kh < 2; ++kh)
                bfr[ni][kh] = *(const bf16x8*)(sB + ni * 2048 + boff[kh]);
        // drain my reads so the barrier certifies A-buf + B[par] fully consumed
        asm volatile("s_waitcnt lgkmcnt(0)" ::: "memory");
        GBAR();

        // refill: A(t+1) into the single A-buf, B(t+2) into B[par]
        if (t + 1 < NT) STAGE_A(t + 1);
        if (t + 2 < NT) STAGE_B(par, t + 2);
        __builtin_amdgcn_s_setprio(1);
#pragma unroll
        for (int mi = 0; mi < 4; ++mi)
#pragma unroll
            for (int ni = 0; ni < 4; ++ni)
#pragma unroll
                for (int kh = 0; kh < 2; ++kh)
                    acc[mi][ni] = __builtin_amdgcn_mfma_f32_16x16x32_bf16(
                        afr[mi][kh], bfr[ni][kh], acc[mi][ni], 0, 0, 0);
        __builtin_amdgcn_s_setprio(0);
        if (t + 2 < NT) {
            // queue: B(t+1):4, A(t+1):4, B(t+2):4 -> drain oldest 8
            asm volatile("s_waitcnt vmcnt(4)" ::: "memory");
        } else {
            asm volatile("s_waitcnt vmcnt(0)" ::: "memory");
        }
        GBAR();
    }
#undef STAGE_A
#undef STAGE_B

    // ---- epilogue: per-wave 64x64 at (wm,wn) ----
    const int growb = bm * 128 + wm * 64;
    const int gcolb = bn * 128 + wn * 64;
#pragma unroll
    for (int mi = 0; mi < 4; ++mi) {
#pragma unroll
        for (int ni = 0; ni < 4; ++ni) {
            const int gcol = gcolb + ni * 16 + l16;
            const float bv = bias[gcol];
#pragma unroll
            for (int r = 0; r < 4; ++r) {
                const int grow = growb + mi * 16 + q4 * 4 + r;
                float v = acc[mi][ni][r] + bv;
                size_t idx = (size_t)grow * N + gcol;
                if (EPI == 0) {
                    ((bf16*)out)[idx] = __float2bfloat16(v);
                } else if (EPI == 1) {
                    float u = 1.5957691216f * (v + 0.044715f * v * v * v);
                    float g = v / (1.f + __expf(-u));
                    ((bf16*)out)[idx] = __float2bfloat16(g);
                } else {
                    ((float*)out)[idx] = v + add[idx];
                }
            }
        }
    }
}

// ---------------- MFMA differential attention + subln ----------------
union U8 { bf16x8 v; uint4 u4; uint2 u2[2]; unsigned short e[8]; };

__global__ __launch_bounds__(256) void attn_mfma(
    const bf16* __restrict__ qkv,
    const float* __restrict__ lq1, const float* __restrict__ lk1,
    const float* __restrict__ lq2, const float* __restrict__ lk2,
    const float* __restrict__ subln_w, bf16* __restrict__ out)
{
    __shared__ __align__(16) bf16 Kp[256 * 136];   // 69632 B
    __shared__ __align__(16) bf16 VT[80 * 264];    // 42240 B
    __shared__ __align__(16) bf16 Pb[4 * 16 * 264];// 33792 B   (total 145664)

    const int tid = threadIdx.x;
    const int h = blockIdx.x & 15;
    const int b = blockIdx.x >> 4;
    const size_t tokbase = (size_t)b * kS;

    float s1 = 0.f, s2 = 0.f;
    for (int i = 0; i < kHD2; ++i) { s1 += lq1[i] * lk1[i]; s2 += lq2[i] * lk2[i]; }
    const float lam = __expf(s1) - __expf(s2) + kLambdaInit;

    for (int c = tid; c < 256 * 34; c += 256) {
        int row = c / 34, s4 = (c - row * 34) * 4;
        uint2 val = make_uint2(0u, 0u);
        const bf16* kg = qkv + (tokbase + row) * kQKV + kE + h * 72;
        if (s4 < 36)                    val = *(const uint2*)(kg + s4);
        else if (s4 >= 64 && s4 < 100)  val = *(const uint2*)(kg + s4 - 28);
        *(uint2*)(Kp + row * 136 + s4) = val;
    }
    for (int c = tid; c < 256 * 18; c += 256) {
        int j = c / 18, s4 = (c - j * 18) * 4;
        union { uint2 u; unsigned short e[4]; } uu;
        uu.u = *(const uint2*)(qkv + (tokbase + j) * kQKV + 2 * kE + h * 72 + s4);
#pragma unroll
        for (int x = 0; x < 4; ++x)
            ((unsigned short*)VT)[(s4 + x) * 264 + j] = uu.e[x];
    }
    for (int c = tid; c < 8 * 256; c += 256) {
        int d = 72 + (c >> 8), j = c & 255;
        ((unsigned short*)VT)[d * 264 + j] = 0;
    }
    __syncthreads();

    const int w = tid >> 6, lane = tid & 63, quad = lane >> 4, l16 = lane & 15;
    bf16* Pw = Pb + w * (16 * 264);
    const float sc = 0.117851130f;            // 1/sqrt(72)
    const float oscale = 1.f - kLambdaInit;

    float sw[5];
#pragma unroll
    for (int dt = 0; dt < 5; ++dt) {
        int d = dt * 16 + l16;
        sw[dt] = (d < 72) ? subln_w[d] : 0.f;
    }

    for (int s = 0; s < 4; ++s) {
        const int q0 = w * 64 + s * 16;
        const bf16* qg = qkv + (tokbase + q0 + l16) * kQKV + h * 72;
        U8 qe0, qe1, qo0, qo1;
        qe0.u4 = *(const uint4*)(qg + quad * 8);
        qe1.u4 = *(const uint4*)(qg + 32);
        qo0.u2[0] = *(const uint2*)(qg + 36 + quad * 8);
        qo0.u2[1] = *(const uint2*)(qg + 40 + quad * 8);
        qo1.u2[0] = *(const uint2*)(qg + 68);
        qo1.u2[1] = *(const uint2*)(qg + 72);
#pragma unroll
        for (int j = 0; j < 8; ++j) {
            bool keep = (quad == 0) && (j < 4);
            if (!keep) { qe1.e[j] = 0; qo1.e[j] = 0; }
        }

        f32x4 se[16], so[16];
#pragma unroll
        for (int t = 0; t < 16; ++t) { se[t] = f32x4{0,0,0,0}; so[t] = f32x4{0,0,0,0}; }
#pragma unroll
        for (int t = 0; t < 16; ++t) {
            const bf16* kr = Kp + (t * 16 + l16) * 136;
            bf16x8 ke0 = *(const bf16x8*)(kr + quad * 8);
            bf16x8 ke1 = *(const bf16x8*)(kr + 32 + quad * 8);
            bf16x8 ko0 = *(const bf16x8*)(kr + 64 + quad * 8);
            bf16x8 ko1 = *(const bf16x8*)(kr + 96 + quad * 8);
            se[t] = __builtin_amdgcn_mfma_f32_16x16x32_bf16(qe0.v, ke0, se[t], 0, 0, 0);
            se[t] = __builtin_amdgcn_mfma_f32_16x16x32_bf16(qe1.v, ke1, se[t], 0, 0, 0);
            so[t] = __builtin_amdgcn_mfma_f32_16x16x32_bf16(qo0.v, ko0, so[t], 0, 0, 0);
            so[t] = __builtin_amdgcn_mfma_f32_16x16x32_bf16(qo1.v, ko1, so[t], 0, 0, 0);
        }

#pragma unroll
        for (int reg = 0; reg < 4; ++reg) {
            float me = -1e30f, mo = -1e30f;
#pragma unroll
            for (int t = 0; t < 16; ++t) {
                me = fmaxf(me, se[t][reg]);
                mo = fmaxf(mo, so[t][reg]);
            }
#pragma unroll
            for (int m = 1; m < 16; m <<= 1) {
                me = fmaxf(me, __shfl_xor(me, m, 64));
                mo = fmaxf(mo, __shfl_xor(mo, m, 64));
            }
            float sume = 0.f, sumo = 0.f;
#pragma unroll
            for (int t = 0; t < 16; ++t) {
                float pe = __expf((se[t][reg] - me) * sc);
                float po = __expf((so[t][reg] - mo) * sc);
                se[t][reg] = pe; sume += pe;
                so[t][reg] = po; sumo += po;
            }
#pragma unroll
            for (int m = 1; m < 16; m <<= 1) {
                sume += __shfl_xor(sume, m, 64);
                sumo += __shfl_xor(sumo, m, 64);
            }
            const float ie = 1.f / sume, io = lam / sumo;
            bf16* prow = Pw + (quad * 4 + reg) * 264;
#pragma unroll
            for (int t = 0; t < 16; ++t) {
                float p = se[t][reg] * ie - so[t][reg] * io;
                prow[t * 16 + l16] = __float2bfloat16(p);
            }
        }

        f32x4 oacc[5];
#pragma unroll
        for (int dt = 0; dt < 5; ++dt) oacc[dt] = f32x4{0,0,0,0};
#pragma unroll
        for (int k0 = 0; k0 < 256; k0 += 32) {
            bf16x8 pf = *(const bf16x8*)(Pw + l16 * 264 + k0 + quad * 8);
#pragma unroll
            for (int dt = 0; dt < 5; ++dt) {
                bf16x8 vf = *(const bf16x8*)(VT + (dt * 16 + l16) * 264 + k0 + quad * 8);
                oacc[dt] = __builtin_amdgcn_mfma_f32_16x16x32_bf16(pf, vf, oacc[dt], 0, 0, 0);
            }
        }

#pragma unroll
        for (int reg = 0; reg < 4; ++reg) {
            float ssq = 0.f;
#pragma unroll
            for (int dt = 0; dt < 5; ++dt) {
                float v = oacc[dt][reg];
                if (dt < 4 || l16 < 8) ssq += v * v;
            }
#pragma unroll
            for (int m = 1; m < 16; m <<= 1) ssq += __shfl_xor(ssq, m, 64);
            float scale = rsqrtf(ssq * (1.f / 72.f) + kSublnEps) * oscale;
            size_t orow = (tokbase + q0 + quad * 4 + reg) * (size_t)kE + h * 72;
#pragma unroll
            for (int dt = 0; dt < 5; ++dt) {
                int d = dt * 16 + l16;
                if (d < 72)
                    out[orow + d] = __float2bfloat16(oacc[dt][reg] * scale * sw[dt]);
            }
        }
    }
}

// ---------------- launch ----------------
extern "C" void kernel_launch(void* const* d_in, const int* in_sizes, int n_in,
                              void* d_out, int out_size, void* d_ws, size_t ws_size,
                              hipStream_t stream)
{
    const float* hidden = (const float*)d_in[0];
    const float* Wq = (const float*)d_in[1];
    const float* bq = (const float*)d_in[2];
    const float* Wk = (const float*)d_in[3];
    const float* bk = (const float*)d_in[4];
    const float* Wv = (const float*)d_in[5];
    const float* bv = (const float*)d_in[6];
    const float* Wo = (const float*)d_in[7];
    const float* bo = (const float*)d_in[8];
    const float* lq1 = (const float*)d_in[9];
    const float* lk1 = (const float*)d_in[10];
    const float* lq2 = (const float*)d_in[11];
    const float* lk2 = (const float*)d_in[12];
    const float* subln_w = (const float*)d_in[13];
    const float* rms1_w = (const float*)d_in[14];
    const float* rms2_w = (const float*)d_in[15];
    const float* fc1_w = (const float*)d_in[16];
    const float* fc1_b = (const float*)d_in[17];
    const float* fc2_w = (const float*)d_in[18];
    const float* fc2_b = (const float*)d_in[19];
    float* outp = (float*)d_out;

    char* wsp = (char*)d_ws;
    size_t off = 0;
    auto alloc = [&](size_t bytes) {
        char* p = wsp + off;
        off += (bytes + 255) & ~(size_t)255;
        return p;
    };
    bf16* wqkv = (bf16*)alloc((size_t)kQKV * kE * 2);
    bf16* wo   = (bf16*)alloc((size_t)kE * kE * 2);
    bf16* w1   = (bf16*)alloc((size_t)kFFP * kE * 2);
    bf16* w2   = (bf16*)alloc((size_t)kE * kFFP * 2);
    float* bqkv = (float*)alloc((size_t)kQKV * 4);
    float* b1   = (float*)alloc((size_t)kFFP * 4);
    bf16* xb    = (bf16*)alloc((size_t)kT * kE * 2);
    bf16* big   = (bf16*)alloc((size_t)kT * kFFP * 2);
    (void)ws_size;

    convert_all<<<(int)((kCvtTotal / 4 + 255) / 256), 256, 0, stream>>>(
        Wq, Wk, Wv, Wo, fc1_w, fc2_w, wqkv, wo, w1, w2);
    prep_bias<<<17, 256, 0, stream>>>(bq, bk, bv, fc1_b, bqkv, b1);

    rmsnorm_kernel<<<kT, 256, 0, stream>>>(hidden, rms1_w, xb, kRmsEps);
    // qkv projection: [8192,1152] x [3456,1152]^T -> big [8192,3456] bf16
    gemm128<0><<<dim3(kQKV / 128, kT / 128), 256, 0, stream>>>(
        xb, wqkv, bqkv, nullptr, big, kQKV, kE, kE);
    attn_mfma<<<kB * kH, 256, 0, stream>>>(
        big, lq1, lk1, lq2, lk2, subln_w, xb);
    // h = attn @ Wo^T + bo + hidden -> d_out (fp32), N=1152 exact
    gemm128<2><<<dim3(kE / 128, kT / 128), 256, 0, stream>>>(
        xb, wo, bo, hidden, d_out, kE, kE, kE);
    rmsnorm_kernel<<<kT, 256, 0, stream>>>(outp, rms2_w, xb, kRmsEps);
    gemm128<1><<<dim3(kFFP / 128, kT / 128), 256, 0, stream>>>(
        xb, w1, b1, nullptr, big, kFFP, kE, kE);
    // fc2: [8192,4352] x [1152,4352]^T; += h (in d_out) + bias -> d_out
    gemm128<2><<<dim3(kE / 128, kT / 128), 256, 0, stream>>>(
        big, w2, fc2_b, outp, d_out, kE, kFFP, kFFP);
}

// Round 9
// 559.391 us; speedup vs baseline: 1.2337x; 1.1024x over previous
//
#include <hip/hip_runtime.h>
#include <hip/hip_bf16.h>

typedef __hip_bfloat16 bf16;
typedef __attribute__((ext_vector_type(4))) float f32x4;
typedef __attribute__((ext_vector_type(8))) __bf16 bf16x8;

constexpr int kE   = 1152;
constexpr int kH   = 16;
constexpr int kHD2 = 36;
constexpr int kFF  = 4304;
constexpr int kFFP = 4352;   // padded to 34*128
constexpr int kB   = 32;
constexpr int kS   = 256;
constexpr int kT   = kB * kS;      // 8192 tokens
constexpr int kQKV = 3456;         // 3*E (27*128, exact)
constexpr float kLambdaInit = 0.7778701f;   // 0.8 - 0.6*exp(-0.3*11)
constexpr float kRmsEps = 1e-6f;
constexpr float kSublnEps = 1e-5f;

__device__ inline void async_copy16(const void* gsrc, void* ldst) {
    __builtin_amdgcn_global_load_lds(
        (__attribute__((address_space(1))) void*)gsrc,
        (__attribute__((address_space(3))) void*)ldst, 16, 0, 0);
}

// ---------------- fused weight convert / pad, 4 elems/thread ----------------
constexpr int  kNEE  = kE * kE;                        // 1327104
constexpr long kSeg0 = 3L * kNEE;                      // wqkv [3456][1152]
constexpr long kSeg1 = kSeg0 + kNEE;                   // wo   [1152][1152]
constexpr long kSeg2 = kSeg1 + (long)kFFP * kE;        // w1   [4352][1152]
constexpr long kCvtTotal = kSeg2 + (long)kE * kFFP;    // w2   [1152][4352]

__global__ __launch_bounds__(256) void convert_all(
    const float* __restrict__ Wq, const float* __restrict__ Wk,
    const float* __restrict__ Wv, const float* __restrict__ Wo,
    const float* __restrict__ f1, const float* __restrict__ f2,
    bf16* __restrict__ wqkv, bf16* __restrict__ wo,
    bf16* __restrict__ w1, bf16* __restrict__ w2)
{
    long i = ((long)blockIdx.x * 256 + threadIdx.x) * 4;
    if (i >= kCvtTotal) return;
    float4 v = make_float4(0.f, 0.f, 0.f, 0.f);
    bf16* dst;
    if (i < kSeg0) {                       // wqkv, exact (no pad)
        long j = i;
        const float* src = (j < kNEE) ? Wq : (j < 2L * kNEE) ? Wk : Wv;
        v = *(const float4*)(src + (j % kNEE));
        dst = wqkv + j;
    } else if (i < kSeg1) {                // wo, exact
        long j = i - kSeg0;
        v = *(const float4*)(Wo + j);
        dst = wo + j;
    } else if (i < kSeg2) {                // w1 [4352][1152], rows>=4304 zero
        long j = i - kSeg1;
        if (j < (long)kFF * kE) v = *(const float4*)(f1 + j);
        dst = w1 + j;
    } else {                               // w2 [1152][4352], cols>=4304 zero
        long j = i - kSeg2;
        int n = (int)(j / kFFP), k = (int)(j - (long)n * kFFP);
        if (k < kFF) v = *(const float4*)(f2 + (long)n * kFF + k);
        dst = w2 + j;
    }
    union { uint2 u; bf16 e[4]; } o;
    o.e[0] = __float2bfloat16(v.x); o.e[1] = __float2bfloat16(v.y);
    o.e[2] = __float2bfloat16(v.z); o.e[3] = __float2bfloat16(v.w);
    *(uint2*)dst = o.u;
}

__global__ __launch_bounds__(256) void prep_bias(
    const float* __restrict__ bq, const float* __restrict__ bk,
    const float* __restrict__ bv, const float* __restrict__ fb,
    float* __restrict__ bqkv, float* __restrict__ fbp)
{
    int i = blockIdx.x * 256 + threadIdx.x;
    if (i < kQKV) {
        float v = (i < kE) ? bq[i] : (i < 2 * kE) ? bk[i - kE] : bv[i - 2 * kE];
        bqkv[i] = v;
    }
    if (i < kFFP) fbp[i] = (i < kFF) ? fb[i] : 0.f;
}

// ---------------- RMSNorm (fp32 in -> bf16 out) ----------------
__global__ __launch_bounds__(256) void rmsnorm_kernel(
    const float* __restrict__ x, const float* __restrict__ w,
    bf16* __restrict__ out, float eps)
{
    int row = blockIdx.x;
    const float* xr = x + (size_t)row * kE;
    float vals[5];
    float ss = 0.f;
    int n = 0;
    for (int j = threadIdx.x; j < kE; j += 256) {
        float v = xr[j];
        vals[n++] = v;
        ss += v * v;
    }
    for (int m = 32; m > 0; m >>= 1) ss += __shfl_xor(ss, m, 64);
    __shared__ float red[4];
    if ((threadIdx.x & 63) == 0) red[threadIdx.x >> 6] = ss;
    __syncthreads();
    float tot = red[0] + red[1] + red[2] + red[3];
    float scale = rsqrtf(tot / (float)kE + eps);
    n = 0;
    for (int j = threadIdx.x; j < kE; j += 256)
        out[(size_t)row * kE + j] = __float2bfloat16(vals[n++] * scale * w[j]);
}

// ---- bf16 NT GEMM, 128Mx128N tile, 64x64/wave, BK=64, 3 blocks/CU ----
// (frozen at R8 structure: ~31% MfmaUtil plateau of the 2-barrier family)
#define GBAR() do { asm volatile("" ::: "memory"); \
                    __builtin_amdgcn_s_barrier();  \
                    asm volatile("" ::: "memory"); } while (0)

template <int EPI>
__global__ __launch_bounds__(256, 3) void gemm128(
    const bf16* __restrict__ A, const bf16* __restrict__ Bw,
    const float* __restrict__ bias, const float* add, void* out,
    int N, int K, int ldk)
{
    // [A 128x128B][B par0 128x128B][B par1 128x128B]
    __shared__ __align__(16) char sm[49152];

    const int tid  = threadIdx.x;
    const int lane = tid & 63;
    const int wave = tid >> 6;
    const int wm   = wave >> 1;        // 0,1: M-half (64 rows)
    const int wn   = wave & 1;         // 0,1: N-half (64 cols)
    const int q4   = lane >> 4;
    const int l16  = lane & 15;

    // XCD-strip locality map (gridDim.y == 64 == 8 XCDs x 8 bm rows)
    const int orig = blockIdx.y * gridDim.x + blockIdx.x;
    const int xcd  = orig & 7;
    const int loc  = orig >> 3;
    const int bm   = xcd * 8 + (loc & 7);
    const int bn   = loc >> 3;

    const int NT = K >> 6;

    // staging: linear LDS dest (gload_lds constraint), pre-swizzled global col.
    const int trow = tid >> 3;                               // 0..31
    const int tswz = ((tid & 7) ^ (trow & 7)) << 4;
    const size_t rs = (size_t)ldk * 2;
    const char* aG = (const char*)A + (size_t)(bm * 128 + trow) * rs + tswz;
    const char* bG = (const char*)Bw + (size_t)(bn * 128 + trow) * rs + tswz;

#define STAGE_A(tt)                                                             \
    {                                                                           \
        const size_t kb = (size_t)(tt) * 128;                                   \
        async_copy16(aG + kb,           sm + tid * 16);                         \
        async_copy16(aG + 32 * rs + kb, sm + tid * 16 + 4096);                  \
        async_copy16(aG + 64 * rs + kb, sm + tid * 16 + 8192);                  \
        async_copy16(aG + 96 * rs + kb, sm + tid * 16 + 12288);                 \
    }
#define STAGE_B(par, tt)                                                        \
    {                                                                           \
        const size_t kb = (size_t)(tt) * 128;                                   \
        char* d = sm + 16384 + (par) * 16384 + tid * 16;                        \
        async_copy16(bG + kb,           d);                                     \
        async_copy16(bG + 32 * rs + kb, d + 4096);                              \
        async_copy16(bG + 64 * rs + kb, d + 8192);                              \
        async_copy16(bG + 96 * rs + kb, d + 12288);                             \
    }

    int aoff[2], boff[2];
#pragma unroll
    for (int kh = 0; kh < 2; ++kh) {
        const int sw = (((kh << 2) + q4) ^ (l16 & 7)) << 4;
        aoff[kh] = (wm * 64 + l16) * 128 + sw;
        boff[kh] = (wn * 64 + l16) * 128 + sw;
    }

    f32x4 acc[4][4] = {};
    bf16x8 afr[4][2], bfr[4][2];

    STAGE_A(0);
    STAGE_B(0, 0);
    if (NT > 1) {
        STAGE_B(1, 1);
        asm volatile("s_waitcnt vmcnt(4)" ::: "memory");
    } else {
        asm volatile("s_waitcnt vmcnt(0)" ::: "memory");
    }
    GBAR();

    for (int t = 0; t < NT; ++t) {
        const int par = t & 1;
        const char* sB = sm + 16384 + par * 16384;

#pragma unroll
        for (int mi = 0; mi < 4; ++mi)
#pragma unroll
            for (int kh = 0; kh < 2; ++kh)
                afr[mi][kh] = *(const bf16x8*)(sm + mi * 2048 + aoff[kh]);
#pragma unroll
        for (int ni = 0; ni < 4; ++ni)
#pragma unroll
            for (int kh = 0; kh < 2; ++kh)
                bfr[ni][kh] = *(const bf16x8*)(sB + ni * 2048 + boff[kh]);
        asm volatile("s_waitcnt lgkmcnt(0)" ::: "memory");
        GBAR();

        if (t + 1 < NT) STAGE_A(t + 1);
        if (t + 2 < NT) STAGE_B(par, t + 2);
        __builtin_amdgcn_s_setprio(1);
#pragma unroll
        for (int mi = 0; mi < 4; ++mi)
#pragma unroll
            for (int ni = 0; ni < 4; ++ni)
#pragma unroll
                for (int kh = 0; kh < 2; ++kh)
                    acc[mi][ni] = __builtin_amdgcn_mfma_f32_16x16x32_bf16(
                        afr[mi][kh], bfr[ni][kh], acc[mi][ni], 0, 0, 0);
        __builtin_amdgcn_s_setprio(0);
        if (t + 2 < NT) {
            asm volatile("s_waitcnt vmcnt(4)" ::: "memory");
        } else {
            asm volatile("s_waitcnt vmcnt(0)" ::: "memory");
        }
        GBAR();
    }
#undef STAGE_A
#undef STAGE_B

    const int growb = bm * 128 + wm * 64;
    const int gcolb = bn * 128 + wn * 64;
#pragma unroll
    for (int mi = 0; mi < 4; ++mi) {
#pragma unroll
        for (int ni = 0; ni < 4; ++ni) {
            const int gcol = gcolb + ni * 16 + l16;
            const float bv = bias[gcol];
#pragma unroll
            for (int r = 0; r < 4; ++r) {
                const int grow = growb + mi * 16 + q4 * 4 + r;
                float v = acc[mi][ni][r] + bv;
                size_t idx = (size_t)grow * N + gcol;
                if (EPI == 0) {
                    ((bf16*)out)[idx] = __float2bfloat16(v);
                } else if (EPI == 1) {
                    float u = 1.5957691216f * (v + 0.044715f * v * v * v);
                    float g = v / (1.f + __expf(-u));
                    ((bf16*)out)[idx] = __float2bfloat16(g);
                } else {
                    ((float*)out)[idx] = v + add[idx];
                }
            }
        }
    }
}

// ---------------- MFMA differential attention + subln ----------------
// 8 waves (512 thr) per (b,h) block -> 2 waves/SIMD (was 1: zero TLP).
// Kp compacted: e at cols 0..39, o at cols 40..79, row stride 88 (16B-aligned,
// 2-way bank aliasing = free). Pad cols staged as zeros (NaN safety).
// LDS: Kp 45056 + VT 42240 + Pb 67584 = 154880 B (fits 160 KiB).
union U8 { bf16x8 v; uint4 u4; uint2 u2[2]; unsigned short e[8]; };

__global__ __launch_bounds__(512, 2) void attn_mfma(
    const bf16* __restrict__ qkv,
    const float* __restrict__ lq1, const float* __restrict__ lk1,
    const float* __restrict__ lq2, const float* __restrict__ lk2,
    const float* __restrict__ subln_w, bf16* __restrict__ out)
{
    __shared__ __align__(16) bf16 Kp[256 * 88];    // 45056 B
    __shared__ __align__(16) bf16 VT[80 * 264];    // 42240 B
    __shared__ __align__(16) bf16 Pb[8 * 16 * 264];// 67584 B

    const int tid = threadIdx.x;
    const int h = blockIdx.x & 15;
    const int b = blockIdx.x >> 4;
    const size_t tokbase = (size_t)b * kS;

    float s1 = 0.f, s2 = 0.f;
    for (int i = 0; i < kHD2; ++i) { s1 += lq1[i] * lk1[i]; s2 += lq2[i] * lk2[i]; }
    const float lam = __expf(s1) - __expf(s2) + kLambdaInit;

    // K staging: row = token, e-half dims 0..35 -> cols 0..35 (36..39 zero),
    // o-half dims 36..71 -> cols 40..75 (76..87 zero). 22 uint2 slots/row.
    for (int c = tid; c < 256 * 22; c += 512) {
        int row = c / 22, s4 = (c - row * 22) * 4;
        uint2 val = make_uint2(0u, 0u);
        const bf16* kg = qkv + (tokbase + row) * kQKV + kE + h * 72;
        if (s4 < 36)                    val = *(const uint2*)(kg + s4);
        else if (s4 >= 40 && s4 <= 72)  val = *(const uint2*)(kg + s4 - 4);
        *(uint2*)(Kp + row * 88 + s4) = val;
    }
    for (int c = tid; c < 256 * 18; c += 512) {
        int j = c / 18, s4 = (c - j * 18) * 4;
        union { uint2 u; unsigned short e[4]; } uu;
        uu.u = *(const uint2*)(qkv + (tokbase + j) * kQKV + 2 * kE + h * 72 + s4);
#pragma unroll
        for (int x = 0; x < 4; ++x)
            ((unsigned short*)VT)[(s4 + x) * 264 + j] = uu.e[x];
    }
    for (int c = tid; c < 8 * 256; c += 512) {
        int d = 72 + (c >> 8), j = c & 255;
        ((unsigned short*)VT)[d * 264 + j] = 0;
    }
    __syncthreads();

    const int w = tid >> 6, lane = tid & 63, quad = lane >> 4, l16 = lane & 15;
    bf16* Pw = Pb + w * (16 * 264);
    const float sc = 0.117851130f;            // 1/sqrt(72)
    const float oscale = 1.f - kLambdaInit;

    float sw[5];
#pragma unroll
    for (int dt = 0; dt < 5; ++dt) {
        int d = dt * 16 + l16;
        sw[dt] = (d < 72) ? subln_w[d] : 0.f;
    }

    for (int s = 0; s < 2; ++s) {
        const int q0 = w * 32 + s * 16;
        const bf16* qg = qkv + (tokbase + q0 + l16) * kQKV + h * 72;
        U8 qe0, qe1, qo0, qo1;
        qe0.u4 = *(const uint4*)(qg + quad * 8);
        qe1.u4 = *(const uint4*)(qg + 32);
        qo0.u2[0] = *(const uint2*)(qg + 36 + quad * 8);
        qo0.u2[1] = *(const uint2*)(qg + 40 + quad * 8);
        qo1.u2[0] = *(const uint2*)(qg + 68);
        qo1.u2[1] = *(const uint2*)(qg + 72);
#pragma unroll
        for (int j = 0; j < 8; ++j) {
            bool keep = (quad == 0) && (j < 4);
            if (!keep) { qe1.e[j] = 0; qo1.e[j] = 0; }
        }

        f32x4 se[16], so[16];
#pragma unroll
        for (int t = 0; t < 16; ++t) { se[t] = f32x4{0,0,0,0}; so[t] = f32x4{0,0,0,0}; }
#pragma unroll
        for (int t = 0; t < 16; ++t) {
            const bf16* kr = Kp + (t * 16 + l16) * 88;
            bf16x8 ke0 = *(const bf16x8*)(kr + quad * 8);
            bf16x8 ke1 = *(const bf16x8*)(kr + 32);
            bf16x8 ko0 = *(const bf16x8*)(kr + 40 + quad * 8);
            bf16x8 ko1 = *(const bf16x8*)(kr + 72);
            se[t] = __builtin_amdgcn_mfma_f32_16x16x32_bf16(qe0.v, ke0, se[t], 0, 0, 0);
            se[t] = __builtin_amdgcn_mfma_f32_16x16x32_bf16(qe1.v, ke1, se[t], 0, 0, 0);
            so[t] = __builtin_amdgcn_mfma_f32_16x16x32_bf16(qo0.v, ko0, so[t], 0, 0, 0);
            so[t] = __builtin_amdgcn_mfma_f32_16x16x32_bf16(qo1.v, ko1, so[t], 0, 0, 0);
        }

#pragma unroll
        for (int reg = 0; reg < 4; ++reg) {
            float me = -1e30f, mo = -1e30f;
#pragma unroll
            for (int t = 0; t < 16; ++t) {
                me = fmaxf(me, se[t][reg]);
                mo = fmaxf(mo, so[t][reg]);
            }
#pragma unroll
            for (int m = 1; m < 16; m <<= 1) {
                me = fmaxf(me, __shfl_xor(me, m, 64));
                mo = fmaxf(mo, __shfl_xor(mo, m, 64));
            }
            float sume = 0.f, sumo = 0.f;
#pragma unroll
            for (int t = 0; t < 16; ++t) {
                float pe = __expf((se[t][reg] - me) * sc);
                float po = __expf((so[t][reg] - mo) * sc);
                se[t][reg] = pe; sume += pe;
                so[t][reg] = po; sumo += po;
            }
#pragma unroll
            for (int m = 1; m < 16; m <<= 1) {
                sume += __shfl_xor(sume, m, 64);
                sumo += __shfl_xor(sumo, m, 64);
            }
            const float ie = 1.f / sume, io = lam / sumo;
            bf16* prow = Pw + (quad * 4 + reg) * 264;
#pragma unroll
            for (int t = 0; t < 16; ++t) {
                float p = se[t][reg] * ie - so[t][reg] * io;
                prow[t * 16 + l16] = __float2bfloat16(p);
            }
        }

        f32x4 oacc[5];
#pragma unroll
        for (int dt = 0; dt < 5; ++dt) oacc[dt] = f32x4{0,0,0,0};
#pragma unroll
        for (int k0 = 0; k0 < 256; k0 += 32) {
            bf16x8 pf = *(const bf16x8*)(Pw + l16 * 264 + k0 + quad * 8);
#pragma unroll
            for (int dt = 0; dt < 5; ++dt) {
                bf16x8 vf = *(const bf16x8*)(VT + (dt * 16 + l16) * 264 + k0 + quad * 8);
                oacc[dt] = __builtin_amdgcn_mfma_f32_16x16x32_bf16(pf, vf, oacc[dt], 0, 0, 0);
            }
        }

#pragma unroll
        for (int reg = 0; reg < 4; ++reg) {
            float ssq = 0.f;
#pragma unroll
            for (int dt = 0; dt < 5; ++dt) {
                float v = oacc[dt][reg];
                if (dt < 4 || l16 < 8) ssq += v * v;
            }
#pragma unroll
            for (int m = 1; m < 16; m <<= 1) ssq += __shfl_xor(ssq, m, 64);
            float scale = rsqrtf(ssq * (1.f / 72.f) + kSublnEps) * oscale;
            size_t orow = (tokbase + q0 + quad * 4 + reg) * (size_t)kE + h * 72;
#pragma unroll
            for (int dt = 0; dt < 5; ++dt) {
                int d = dt * 16 + l16;
                if (d < 72)
                    out[orow + d] = __float2bfloat16(oacc[dt][reg] * scale * sw[dt]);
            }
        }
    }
}

// ---------------- launch ----------------
extern "C" void kernel_launch(void* const* d_in, const int* in_sizes, int n_in,
                              void* d_out, int out_size, void* d_ws, size_t ws_size,
                              hipStream_t stream)
{
    const float* hidden = (const float*)d_in[0];
    const float* Wq = (const float*)d_in[1];
    const float* bq = (const float*)d_in[2];
    const float* Wk = (const float*)d_in[3];
    const float* bk = (const float*)d_in[4];
    const float* Wv = (const float*)d_in[5];
    const float* bv = (const float*)d_in[6];
    const float* Wo = (const float*)d_in[7];
    const float* bo = (const float*)d_in[8];
    const float* lq1 = (const float*)d_in[9];
    const float* lk1 = (const float*)d_in[10];
    const float* lq2 = (const float*)d_in[11];
    const float* lk2 = (const float*)d_in[12];
    const float* subln_w = (const float*)d_in[13];
    const float* rms1_w = (const float*)d_in[14];
    const float* rms2_w = (const float*)d_in[15];
    const float* fc1_w = (const float*)d_in[16];
    const float* fc1_b = (const float*)d_in[17];
    const float* fc2_w = (const float*)d_in[18];
    const float* fc2_b = (const float*)d_in[19];
    float* outp = (float*)d_out;

    char* wsp = (char*)d_ws;
    size_t off = 0;
    auto alloc = [&](size_t bytes) {
        char* p = wsp + off;
        off += (bytes + 255) & ~(size_t)255;
        return p;
    };
    bf16* wqkv = (bf16*)alloc((size_t)kQKV * kE * 2);
    bf16* wo   = (bf16*)alloc((size_t)kE * kE * 2);
    bf16* w1   = (bf16*)alloc((size_t)kFFP * kE * 2);
    bf16* w2   = (bf16*)alloc((size_t)kE * kFFP * 2);
    float* bqkv = (float*)alloc((size_t)kQKV * 4);
    float* b1   = (float*)alloc((size_t)kFFP * 4);
    bf16* xb    = (bf16*)alloc((size_t)kT * kE * 2);
    bf16* big   = (bf16*)alloc((size_t)kT * kFFP * 2);
    (void)ws_size;

    convert_all<<<(int)((kCvtTotal / 4 + 255) / 256), 256, 0, stream>>>(
        Wq, Wk, Wv, Wo, fc1_w, fc2_w, wqkv, wo, w1, w2);
    prep_bias<<<17, 256, 0, stream>>>(bq, bk, bv, fc1_b, bqkv, b1);

    rmsnorm_kernel<<<kT, 256, 0, stream>>>(hidden, rms1_w, xb, kRmsEps);
    // qkv projection: [8192,1152] x [3456,1152]^T -> big [8192,3456] bf16
    gemm128<0><<<dim3(kQKV / 128, kT / 128), 256, 0, stream>>>(
        xb, wqkv, bqkv, nullptr, big, kQKV, kE, kE);
    attn_mfma<<<kB * kH, 512, 0, stream>>>(
        big, lq1, lk1, lq2, lk2, subln_w, xb);
    // h = attn @ Wo^T + bo + hidden -> d_out (fp32), N=1152 exact
    gemm128<2><<<dim3(kE / 128, kT / 128), 256, 0, stream>>>(
        xb, wo, bo, hidden, d_out, kE, kE, kE);
    rmsnorm_kernel<<<kT, 256, 0, stream>>>(outp, rms2_w, xb, kRmsEps);
    gemm128<1><<<dim3(kFFP / 128, kT / 128), 256, 0, stream>>>(
        xb, w1, b1, nullptr, big, kFFP, kE, kE);
    // fc2: [8192,4352] x [1152,4352]^T; += h (in d_out) + bias -> d_out
    gemm128<2><<<dim3(kE / 128, kT / 128), 256, 0, stream>>>(
        big, w2, fc2_b, outp, d_out, kE, kFFP, kFFP);
}